// Round 3
// baseline (1745.071 us; speedup 1.0000x reference)
//
#include <hip/hip_runtime.h>
#include <hip/hip_bf16.h>
#include <math.h>

namespace {

constexpr int Bb = 16;
constexpr int Ss = 1024;
constexpr int Dd = 1024;
constexpr int Hh = 16;
constexpr int HD = 64;
constexpr int MLPH = 2730;
constexpr int MLPH_PAD = 2752;
constexpr int ADA_LD = 6144;
constexpr int NR = Bb * Ss; // 16384 rows

typedef __attribute__((ext_vector_type(8))) short bf16x8;
typedef __attribute__((ext_vector_type(4))) float f32x4;
typedef __hip_bfloat16 bf16;

__device__ __forceinline__ float bf2f(bf16 v){ return __bfloat162float(v); }
__device__ __forceinline__ bf16 f2bf(float v){ return __float2bfloat16(v); }
__device__ __forceinline__ short f2bfs(float v){ bf16 t = __float2bfloat16(v); return __builtin_bit_cast(short, t); }

__device__ __forceinline__ f32x4 mfma16(bf16x8 a, bf16x8 b, f32x4 c){
  return __builtin_amdgcn_mfma_f32_16x16x32_bf16(a, b, c, 0, 0, 0);
}

// ---------------- small kernels ----------------

__global__ void k_silu(const float* __restrict__ c, float* __restrict__ out, int n){
  int i = blockIdx.x*256 + threadIdx.x;
  if(i < n){ float v = c[i]; out[i] = v / (1.f + __expf(-v)); }
}

__global__ __launch_bounds__(256) void k_ada(const float* __restrict__ sc,
    const float* __restrict__ w, const float* __restrict__ bias, float* __restrict__ ada){
  int j = blockIdx.x*256 + threadIdx.x;   // 0..6143
  float acc[Bb];
  #pragma unroll
  for(int b=0;b<Bb;++b) acc[b] = 0.f;
  for(int k=0;k<Dd;++k){
    float wv = w[(size_t)k*ADA_LD + j];
    #pragma unroll
    for(int b=0;b<Bb;++b) acc[b] += sc[b*Dd + k] * wv;
  }
  float bv = bias[j];
  #pragma unroll
  for(int b=0;b<Bb;++b) ada[(size_t)b*ADA_LD + j] = acc[b] + bv;
}

__global__ void k_rope_tab(float2* __restrict__ tab){
  int i = blockIdx.x*256 + threadIdx.x;   // 0..32767 ; i = s*32 + f
  int s = i >> 5, f = i & 31;
  float inv = powf(10000.f, -((float)(2*f)) / 64.f);
  float fr = (float)s * inv;
  float sv, cv;
  sincosf(fr, &sv, &cv);
  tab[i] = make_float2(cv, sv);
}

// in f32 [R,C] -> out bf16 [C,Rpad], zero-filled for col in [R,Rpad)
__global__ void k_transpose(const float* __restrict__ in, bf16* __restrict__ out,
                            int R, int C, int Rpad){
  __shared__ short tile[32][33];
  int tx = threadIdx.x & 31, ty = threadIdx.x >> 5;
  int tr0 = blockIdx.x*32, tc0 = blockIdx.y*32;
  #pragma unroll
  for(int i=0;i<4;++i){
    int r = tr0 + ty + i*8, cc = tc0 + tx;
    short v = 0;
    if(r < R && cc < C) v = f2bfs(in[(size_t)r*C + cc]);
    tile[ty+i*8][tx] = v;
  }
  __syncthreads();
  #pragma unroll
  for(int i=0;i<4;++i){
    int oc = tc0 + ty + i*8;   // out row (former col)
    int orow = tr0 + tx;       // out col (former row)
    if(oc < C && orow < Rpad)
      out[(size_t)oc*Rpad + orow] = __builtin_bit_cast(bf16, tile[tx][ty+i*8]);
  }
}

// RMSNorm over D + adaLN modulate: out = (w*x*rsqrt(mean(x^2)+eps))*(1+scale)+shift
__global__ __launch_bounds__(256) void k_norm_mod(const float* __restrict__ x,
    const float* __restrict__ w, const float* __restrict__ shift, const float* __restrict__ scale,
    bf16* __restrict__ out){
  int r = blockIdx.x;
  int b = r >> 10;
  int t = threadIdx.x;
  const float* xr = x + (size_t)r*Dd;
  float v[4]; float ss = 0.f;
  #pragma unroll
  for(int i=0;i<4;++i){
    float f = xr[t*4+i];
    v[i] = f; ss += f*f;
  }
  #pragma unroll
  for(int m=1;m<64;m<<=1) ss += __shfl_xor(ss, m);
  __shared__ float red[4];
  if((t & 63) == 0) red[t>>6] = ss;
  __syncthreads();
  float tot = red[0]+red[1]+red[2]+red[3];
  float rms = rsqrtf(tot * (1.f/Dd) + 1e-6f);
  #pragma unroll
  for(int i=0;i<4;++i){
    int ccol = t*4+i;
    float h = v[i]*rms*w[ccol];
    float scv = scale[(size_t)b*ADA_LD + ccol];
    float shv = shift[(size_t)b*ADA_LD + ccol];
    out[(size_t)r*Dd + ccol] = f2bf(h*(1.f+scv) + shv);
  }
}

// per-(b,s,h) RMSNorm(64) + RoPE for q and k rows of qkv, in place
__global__ __launch_bounds__(256) void k_qknorm(bf16* __restrict__ qkv,
    const float* __restrict__ qw, const float* __restrict__ kw, const float2* __restrict__ tab){
  int gid = blockIdx.x*256 + threadIdx.x;
  int lane = gid & 63;
  int wid = gid >> 6;          // 0 .. 524287
  int isK = wid & 1;
  int bsh = wid >> 1;          // 0 .. 262143
  int h = bsh & (Hh-1);
  int bs = bsh >> 4;           // 0..16383
  int s = bs & (Ss-1);
  bf16* p = qkv + (size_t)bs*3072 + isK*Dd + h*HD + lane;
  float vv = bf2f(*p);
  float ss = vv*vv;
  #pragma unroll
  for(int m=1;m<64;m<<=1) ss += __shfl_xor(ss, m);
  float rms = rsqrtf(ss*(1.f/HD) + 1e-6f);
  const float* wn = isK ? kw : qw;
  float xn = vv*rms*wn[lane];
  float other = __shfl_xor(xn, 32);
  float2 cs = tab[s*32 + (lane & 31)];
  float o = (lane < 32) ? (xn*cs.x - other*cs.y) : (other*cs.y + xn*cs.x);
  *p = f2bf(o);
}

// ---------------- GEMM: C[M,N] = A[M,K] * BT[N,K]^T (+ epilogues) ----------------
// MODE 0: out bf16 = acc + bias1[n]
// MODE 1: out f32  = x_f32[r,n] + gate[b,n]*(acc + bias1[n])
// MODE 2: out f32  = xmid_f32[r,n] + gate[b,n]*(acc + bias1[n])
// MODE 3: dual-B swiglu: out bf16 = silu(acc1+bias1[n]) * (acc2+bias2[n]); n>=NB -> 0
template<int MODE>
__global__ __launch_bounds__(256) void k_gemm(
    const bf16* __restrict__ A, int lda,
    const bf16* __restrict__ BT, const bf16* __restrict__ BT2, int ldb,
    const float* __restrict__ bias1, const float* __restrict__ bias2,
    int K, int NB,
    const float* __restrict__ res, const float* __restrict__ gate,
    void* __restrict__ outp, int ldo)
{
  constexpr int LDS_S = 40;   // stride: 80B rows -> 16B aligned b128, ~2-way banks
  alignas(16) __shared__ short As[128*LDS_S];
  alignas(16) __shared__ short Bs[128*LDS_S];
  alignas(16) __shared__ short Bs2[(MODE==3)? 128*LDS_S : 8];

  int tid = threadIdx.x;
  int lane = tid & 63, wid = tid >> 6;
  int wm = wid >> 1, wn = wid & 1;
  int l15 = lane & 15, l4 = lane >> 4;
  int brow = blockIdx.x * 128;
  int bcol = blockIdx.y * 128;

  f32x4 zero4 = {0.f,0.f,0.f,0.f};
  f32x4 acc[4][4], acc2[4][4];
  #pragma unroll
  for(int m=0;m<4;++m)
    #pragma unroll
    for(int n=0;n<4;++n){ acc[m][n]=zero4; acc2[m][n]=zero4; }

  const int nk = K >> 5;
  for(int kt=0; kt<nk; ++kt){
    __syncthreads();
    #pragma unroll
    for(int ch=0; ch<2; ++ch){
      int flat = (tid + ch*256)*8;
      int row = flat >> 5, kk = flat & 31;
      bf16x8 va = *(const bf16x8*)(A + (size_t)(brow+row)*lda + (kt<<5) + kk);
      *(bf16x8*)&As[row*LDS_S + kk] = va;
      int n = bcol + row;
      if constexpr (MODE==3){
        bf16x8 z = {0,0,0,0,0,0,0,0};
        bool ok = n < NB;
        bf16x8 v1 = ok ? *(const bf16x8*)(BT  + (size_t)n*ldb + (kt<<5) + kk) : z;
        bf16x8 v2 = ok ? *(const bf16x8*)(BT2 + (size_t)n*ldb + (kt<<5) + kk) : z;
        *(bf16x8*)&Bs[row*LDS_S + kk]  = v1;
        *(bf16x8*)&Bs2[row*LDS_S + kk] = v2;
      } else {
        *(bf16x8*)&Bs[row*LDS_S + kk] = *(const bf16x8*)(BT + (size_t)n*ldb + (kt<<5) + kk);
      }
    }
    __syncthreads();
    bf16x8 af[4], bfr[4], bfr2[4];
    #pragma unroll
    for(int m=0;m<4;++m) af[m] = *(const bf16x8*)&As[(wm*64 + m*16 + l15)*LDS_S + l4*8];
    #pragma unroll
    for(int n=0;n<4;++n) bfr[n] = *(const bf16x8*)&Bs[(wn*64 + n*16 + l15)*LDS_S + l4*8];
    if constexpr (MODE==3){
      #pragma unroll
      for(int n=0;n<4;++n) bfr2[n] = *(const bf16x8*)&Bs2[(wn*64 + n*16 + l15)*LDS_S + l4*8];
    }
    #pragma unroll
    for(int m=0;m<4;++m){
      #pragma unroll
      for(int n=0;n<4;++n){
        acc[m][n] = mfma16(af[m], bfr[n], acc[m][n]);
        if constexpr (MODE==3) acc2[m][n] = mfma16(af[m], bfr2[n], acc2[m][n]);
      }
    }
  }

  // epilogue: C layout col=lane&15, row=(lane>>4)*4+j  [guide-verified]
  #pragma unroll
  for(int m=0;m<4;++m){
    #pragma unroll
    for(int n=0;n<4;++n){
      #pragma unroll
      for(int j=0;j<4;++j){
        int r  = brow + wm*64 + m*16 + l4*4 + j;
        int cc = bcol + wn*64 + n*16 + l15;
        float v = acc[m][n][j];
        if constexpr (MODE==0){
          v += bias1[cc];
          ((bf16*)outp)[(size_t)r*ldo + cc] = f2bf(v);
        } else if constexpr (MODE==1){
          v += bias1[cc];
          int b = r >> 10;
          float xr = res[(size_t)r*Dd + cc];
          ((float*)outp)[(size_t)r*ldo + cc] = xr + gate[(size_t)b*ADA_LD + cc]*v;
        } else if constexpr (MODE==2){
          v += bias1[cc];
          int b = r >> 10;
          float xr = res[(size_t)r*Dd + cc];
          ((float*)outp)[(size_t)r*ldo + cc] = xr + gate[(size_t)b*ADA_LD + cc]*v;
        } else {
          if(cc < MLPH_PAD){
            float o = 0.f;
            if(cc < MLPH){
              float v1 = v + bias1[cc];
              float v2 = acc2[m][n][j] + bias2[cc];
              o = (v1/(1.f+__expf(-v1)))*v2;
            }
            ((bf16*)outp)[(size_t)r*ldo + cc] = f2bf(o);
          }
        }
      }
    }
  }
}

// ---------------- flash attention, per (b,h) and 64-row Q block ----------------
__global__ __launch_bounds__(256) void k_attn(const bf16* __restrict__ qkv, bf16* __restrict__ obuf){
  constexpr int LT = 72;  // 144B rows: 16B-aligned b128, 2-way banks
  alignas(16) __shared__ short Qs[64*LT];
  alignas(16) __shared__ short Ks[64*LT];
  alignas(16) __shared__ short VTs[64*LT];  // [hd][s']
  alignas(16) __shared__ short Ps[64*LT];

  int bh = blockIdx.x;
  int b = bh >> 4, h = bh & 15;
  int qb = blockIdx.y;
  int tid = threadIdx.x;
  int lane = tid & 63, w = tid >> 6;
  int l15 = lane & 15, l4 = lane >> 4;

  const bf16* base = qkv + (size_t)b*Ss*3072 + h*HD;

  #pragma unroll
  for(int ch=0; ch<2; ++ch){
    int flat = (tid + ch*256)*8;
    int row = flat >> 6, col = flat & 63;
    bf16x8 v = *(const bf16x8*)(base + (size_t)(qb*64+row)*3072 + col);
    *(bf16x8*)&Qs[row*LT + col] = v;
  }

  f32x4 zero4 = {0.f,0.f,0.f,0.f};
  f32x4 acc_o[4];
  #pragma unroll
  for(int i=0;i<4;++i) acc_o[i] = zero4;
  float mrow[4], lrow[4];
  #pragma unroll
  for(int j=0;j<4;++j){ mrow[j] = -1e30f; lrow[j] = 0.f; }

  for(int kb=0; kb<Ss/64; ++kb){
    __syncthreads();
    #pragma unroll
    for(int ch=0; ch<2; ++ch){
      int flat = (tid + ch*256)*8;
      int row = flat >> 6, col = flat & 63;
      bf16x8 kv = *(const bf16x8*)(base + Dd + (size_t)(kb*64+row)*3072 + col);
      *(bf16x8*)&Ks[row*LT + col] = kv;
      bf16x8 vv = *(const bf16x8*)(base + 2*Dd + (size_t)(kb*64+row)*3072 + col);
      #pragma unroll
      for(int i=0;i<8;++i) VTs[(col+i)*LT + row] = vv[i];
    }
    __syncthreads();

    // QK^T: wave w owns Q rows w*16..w*16+15, all 64 K cols
    f32x4 sacc[4];
    #pragma unroll
    for(int an=0;an<4;++an) sacc[an]=zero4;
    bf16x8 aq0 = *(const bf16x8*)&Qs[(w*16+l15)*LT + l4*8];
    bf16x8 aq1 = *(const bf16x8*)&Qs[(w*16+l15)*LT + 32 + l4*8];
    #pragma unroll
    for(int an=0;an<4;++an){
      bf16x8 bk0 = *(const bf16x8*)&Ks[(an*16+l15)*LT + l4*8];
      bf16x8 bk1 = *(const bf16x8*)&Ks[(an*16+l15)*LT + 32 + l4*8];
      sacc[an] = mfma16(aq0, bk0, sacc[an]);
      sacc[an] = mfma16(aq1, bk1, sacc[an]);
    }
    const float scale = 0.125f;
    #pragma unroll
    for(int j=0;j<4;++j){
      float mx = -1e30f;
      #pragma unroll
      for(int an=0;an<4;++an){ sacc[an][j] *= scale; mx = fmaxf(mx, sacc[an][j]); }
      #pragma unroll
      for(int msk=1;msk<16;msk<<=1) mx = fmaxf(mx, __shfl_xor(mx, msk));
      float mnew = fmaxf(mrow[j], mx);
      float corr = __expf(mrow[j] - mnew);
      mrow[j] = mnew;
      float psum = 0.f;
      #pragma unroll
      for(int an=0;an<4;++an){
        float p = __expf(sacc[an][j] - mnew);
        sacc[an][j] = p;
        psum += p;
      }
      #pragma unroll
      for(int msk=1;msk<16;msk<<=1) psum += __shfl_xor(psum, msk);
      lrow[j] = lrow[j]*corr + psum;
      #pragma unroll
      for(int an=0;an<4;++an) acc_o[an][j] *= corr;
    }
    // P -> LDS (wave-private rows; within-wave write->read through same array)
    #pragma unroll
    for(int an=0;an<4;++an)
      #pragma unroll
      for(int j=0;j<4;++j)
        Ps[(w*16 + l4*4 + j)*LT + an*16 + l15] = f2bfs(sacc[an][j]);
    bf16x8 pa0 = *(const bf16x8*)&Ps[(w*16+l15)*LT + l4*8];
    bf16x8 pa1 = *(const bf16x8*)&Ps[(w*16+l15)*LT + 32 + l4*8];
    #pragma unroll
    for(int an2=0;an2<4;++an2){
      bf16x8 bv0 = *(const bf16x8*)&VTs[(an2*16+l15)*LT + l4*8];
      bf16x8 bv1 = *(const bf16x8*)&VTs[(an2*16+l15)*LT + 32 + l4*8];
      acc_o[an2] = mfma16(pa0, bv0, acc_o[an2]);
      acc_o[an2] = mfma16(pa1, bv1, acc_o[an2]);
    }
  }
  #pragma unroll
  for(int an2=0;an2<4;++an2)
    #pragma unroll
    for(int j=0;j<4;++j){
      int r = qb*64 + w*16 + l4*4 + j;
      float ov = acc_o[an2][j] / lrow[j];
      obuf[((size_t)b*Ss + r)*Dd + h*HD + an2*16 + l15] = f2bf(ov);
    }
}

} // namespace

extern "C" void kernel_launch(void* const* d_in, const int* in_sizes, int n_in,
                              void* d_out, int out_size, void* d_ws, size_t ws_size,
                              hipStream_t stream){
  // All reference dtypes are float32 (in_npz 132MB / out_npz 62MB confirm).
  const float* x      = (const float*)d_in[0];
  const float* c      = (const float*)d_in[1];
  const float* w_qkv  = (const float*)d_in[2];
  const float* b_qkv  = (const float*)d_in[3];
  const float* w_proj = (const float*)d_in[4];
  const float* b_proj = (const float*)d_in[5];
  const float* w12    = (const float*)d_in[6];
  const float* b12    = (const float*)d_in[7];
  const float* w3     = (const float*)d_in[8];
  const float* b3     = (const float*)d_in[9];
  const float* w_ada  = (const float*)d_in[10];
  const float* b_ada  = (const float*)d_in[11];
  const float* n1w    = (const float*)d_in[12];
  const float* n2w    = (const float*)d_in[13];
  const float* qnw    = (const float*)d_in[14];
  const float* knw    = (const float*)d_in[15];
  float* out = (float*)d_out;
  (void)in_sizes; (void)n_in; (void)out_size;

  // ---- workspace layout (total 227,254,272 B = 216.75 MiB) ----
  constexpr size_t WS_NEED = 227254272ull;
  if (ws_size < WS_NEED) return;  // diagnostic: clean absmax-fail instead of fault

  char* ws = (char*)d_ws;
  float*  silu_c = (float*)(ws + 0);            //  64 KiB  f32 [16,1024]
  float*  ada    = (float*)(ws + 65536);        // 384 KiB  f32 [16,6144]
  float2* ropet  = (float2*)(ws + 458752);      // 256 KiB  [1024,32]
  bf16*   wqkvT  = (bf16*)(ws + 720896);        //   6 MiB  [3072,1024]
  bf16*   wprojT = (bf16*)(ws + 7012352);       //   2 MiB  [1024,1024]
  bf16*   w12T   = (bf16*)(ws + 9109504);       //  10.7MiB [5460,1024]
  bf16*   w3T    = (bf16*)(ws + 20291584);      //   5.4MiB [1024,2752] zero-padded
  bf16*   hbuf   = (bf16*)(ws + 25927680);      //  32 MiB  [16384,1024]
  bf16*   qkvb   = (bf16*)(ws + 59482112);      //  96 MiB  [16384,3072]
  float*  xmid   = (float*)(ws + 160145408);    //  64 MiB  [16384,1024] f32
  bf16*   obuf   = hbuf;   // hbuf dead after QKV GEMM
  bf16*   h2     = hbuf;   // obuf dead after proj GEMM
  bf16*   mlpmid = qkvb;   // qkv dead after attention

  k_silu<<<64,256,0,stream>>>(c, silu_c, Bb*Dd);
  k_rope_tab<<<128,256,0,stream>>>(ropet);
  k_ada<<<24,256,0,stream>>>(silu_c, w_ada, b_ada, ada);
  k_transpose<<<dim3(32,96),256,0,stream>>>(w_qkv, wqkvT, 1024, 3072, 1024);
  k_transpose<<<dim3(32,32),256,0,stream>>>(w_proj, wprojT, 1024, 1024, 1024);
  k_transpose<<<dim3(32,171),256,0,stream>>>(w12, w12T, 1024, 5460, 1024);
  k_transpose<<<dim3(86,32),256,0,stream>>>(w3, w3T, 2730, 1024, 2752);

  // attention branch
  k_norm_mod<<<NR,256,0,stream>>>(x, n1w, ada + 0, ada + 1024, hbuf);
  k_gemm<0><<<dim3(128,24),256,0,stream>>>(hbuf,1024, wqkvT,nullptr,1024,
      b_qkv,nullptr, 1024,0, nullptr,nullptr, qkvb,3072);
  k_qknorm<<<131072,256,0,stream>>>(qkvb, qnw, knw, ropet);
  k_attn<<<dim3(256,16),256,0,stream>>>(qkvb, obuf);
  k_gemm<1><<<dim3(128,8),256,0,stream>>>(obuf,1024, wprojT,nullptr,1024,
      b_proj,nullptr, 1024,0, x, ada + 2048, xmid,1024);

  // MLP branch
  k_norm_mod<<<NR,256,0,stream>>>(xmid, n2w, ada + 3072, ada + 4096, h2);
  k_gemm<3><<<dim3(128,22),256,0,stream>>>(h2,1024, w12T, w12T + (size_t)MLPH*1024, 1024,
      b12, b12 + MLPH, 1024, MLPH, nullptr,nullptr, mlpmid, MLPH_PAD);
  k_gemm<2><<<dim3(128,8),256,0,stream>>>(mlpmid,MLPH_PAD, w3T,nullptr,MLPH_PAD,
      b3,nullptr, MLPH_PAD,0, xmid, ada + 5120, out,1024);
}

// Round 4
// 1671.833 us; speedup vs baseline: 1.0438x; 1.0438x over previous
//
#include <hip/hip_runtime.h>
#include <hip/hip_bf16.h>
#include <math.h>

namespace {

constexpr int Bb = 16;
constexpr int Ss = 1024;
constexpr int Dd = 1024;
constexpr int Hh = 16;
constexpr int HD = 64;
constexpr int MLPH = 2730;
constexpr int MLPH_PAD = 2752;
constexpr int ADA_LD = 6144;
constexpr int NR = Bb * Ss; // 16384 rows

typedef __attribute__((ext_vector_type(8))) short bf16x8;
typedef __attribute__((ext_vector_type(4))) float f32x4;
typedef __hip_bfloat16 bf16;
typedef unsigned int u32;

__device__ __forceinline__ float bf2f(bf16 v){ return __bfloat162float(v); }
__device__ __forceinline__ bf16 f2bf(float v){ return __float2bfloat16(v); }
__device__ __forceinline__ short f2bfs(float v){ bf16 t = __float2bfloat16(v); return __builtin_bit_cast(short, t); }

__device__ __forceinline__ f32x4 mfma16(bf16x8 a, bf16x8 b, f32x4 c){
  return __builtin_amdgcn_mfma_f32_16x16x32_bf16(a, b, c, 0, 0, 0);
}

// async global->LDS, 16B per lane; LDS dest must be linear (base + lane*16)
__device__ __forceinline__ void gload16(const void* g, void* l){
  __builtin_amdgcn_global_load_lds(
      (const __attribute__((address_space(1))) u32*)g,
      (__attribute__((address_space(3))) u32*)l, 16, 0, 0);
}

// ---------------- small kernels ----------------

__global__ void k_silu(const float* __restrict__ c, float* __restrict__ out, int n){
  int i = blockIdx.x*256 + threadIdx.x;
  if(i < n){ float v = c[i]; out[i] = v / (1.f + __expf(-v)); }
}

__global__ __launch_bounds__(256) void k_ada(const float* __restrict__ sc,
    const float* __restrict__ w, const float* __restrict__ bias, float* __restrict__ ada){
  int j = blockIdx.x*256 + threadIdx.x;   // 0..6143
  float acc[Bb];
  #pragma unroll
  for(int b=0;b<Bb;++b) acc[b] = 0.f;
  for(int k=0;k<Dd;++k){
    float wv = w[(size_t)k*ADA_LD + j];
    #pragma unroll
    for(int b=0;b<Bb;++b) acc[b] += sc[b*Dd + k] * wv;
  }
  float bv = bias[j];
  #pragma unroll
  for(int b=0;b<Bb;++b) ada[(size_t)b*ADA_LD + j] = acc[b] + bv;
}

__global__ void k_rope_tab(float2* __restrict__ tab){
  int i = blockIdx.x*256 + threadIdx.x;   // 0..32767 ; i = s*32 + f
  int s = i >> 5, f = i & 31;
  float inv = powf(10000.f, -((float)(2*f)) / 64.f);
  float fr = (float)s * inv;
  float sv, cv;
  sincosf(fr, &sv, &cv);
  tab[i] = make_float2(cv, sv);
}

// in f32 [R,C] -> out bf16 [C,Rpad], zero-filled for col in [R,Rpad)
__global__ void k_transpose(const float* __restrict__ in, bf16* __restrict__ out,
                            int R, int C, int Rpad){
  __shared__ short tile[32][33];
  int tx = threadIdx.x & 31, ty = threadIdx.x >> 5;
  int tr0 = blockIdx.x*32, tc0 = blockIdx.y*32;
  #pragma unroll
  for(int i=0;i<4;++i){
    int r = tr0 + ty + i*8, cc = tc0 + tx;
    short v = 0;
    if(r < R && cc < C) v = f2bfs(in[(size_t)r*C + cc]);
    tile[ty+i*8][tx] = v;
  }
  __syncthreads();
  #pragma unroll
  for(int i=0;i<4;++i){
    int oc = tc0 + ty + i*8;   // out row (former col)
    int orow = tr0 + tx;       // out col (former row)
    if(oc < C && orow < Rpad)
      out[(size_t)oc*Rpad + orow] = __builtin_bit_cast(bf16, tile[tx][ty+i*8]);
  }
}

// RMSNorm over D + adaLN modulate
__global__ __launch_bounds__(256) void k_norm_mod(const float* __restrict__ x,
    const float* __restrict__ w, const float* __restrict__ shift, const float* __restrict__ scale,
    bf16* __restrict__ out){
  int r = blockIdx.x;
  int b = r >> 10;
  int t = threadIdx.x;
  const float* xr = x + (size_t)r*Dd;
  float v[4]; float ss = 0.f;
  #pragma unroll
  for(int i=0;i<4;++i){
    float f = xr[t*4+i];
    v[i] = f; ss += f*f;
  }
  #pragma unroll
  for(int m=1;m<64;m<<=1) ss += __shfl_xor(ss, m);
  __shared__ float red[4];
  if((t & 63) == 0) red[t>>6] = ss;
  __syncthreads();
  float tot = red[0]+red[1]+red[2]+red[3];
  float rms = rsqrtf(tot * (1.f/Dd) + 1e-6f);
  #pragma unroll
  for(int i=0;i<4;++i){
    int ccol = t*4+i;
    float h = v[i]*rms*w[ccol];
    float scv = scale[(size_t)b*ADA_LD + ccol];
    float shv = shift[(size_t)b*ADA_LD + ccol];
    out[(size_t)r*Dd + ccol] = f2bf(h*(1.f+scv) + shv);
  }
}

// per-(b,s,h) RMSNorm(64) + RoPE for q and k rows of qkv, in place
__global__ __launch_bounds__(256) void k_qknorm(bf16* __restrict__ qkv,
    const float* __restrict__ qw, const float* __restrict__ kw, const float2* __restrict__ tab){
  int gid = blockIdx.x*256 + threadIdx.x;
  int lane = gid & 63;
  int wid = gid >> 6;          // 0 .. 524287
  int isK = wid & 1;
  int bsh = wid >> 1;          // 0 .. 262143
  int h = bsh & (Hh-1);
  int bs = bsh >> 4;           // 0..16383
  int s = bs & (Ss-1);
  bf16* p = qkv + (size_t)bs*3072 + isK*Dd + h*HD + lane;
  float vv = bf2f(*p);
  float ss = vv*vv;
  #pragma unroll
  for(int m=1;m<64;m<<=1) ss += __shfl_xor(ss, m);
  float rms = rsqrtf(ss*(1.f/HD) + 1e-6f);
  const float* wn = isK ? kw : qw;
  float xn = vv*rms*wn[lane];
  float other = __shfl_xor(xn, 32);
  float2 cs = tab[s*32 + (lane & 31)];
  float o = (lane < 32) ? (xn*cs.x - other*cs.y) : (other*cs.y + xn*cs.x);
  *p = f2bf(o);
}

// ---------------- GEMM: C[M,N] = A[M,K] * BT[N,K]^T (+ epilogues) ----------------
// m97 structure: linear LDS tiles staged via global_load_lds_dwordx4 (16B/lane),
// 2-barrier K-loop, 4 waves, 4x4 16x16x32 MFMA per wave.
// MODE 0: out bf16 = acc + bias1[n]
// MODE 1: out f32  = res[r,n] + gate[b,n]*(acc + bias1[n])
// MODE 2: same as 1 (kept for call-site clarity)
// MODE 3: dual-B swiglu: out bf16 = silu(acc1+bias1[n]) * (acc2+bias2[n]); n>=NB -> 0
//         (B rows n>=NB read adjacent ws weight data; masked in epilogue)
template<int MODE>
__global__ __launch_bounds__(256) void k_gemm(
    const bf16* __restrict__ A, int lda,
    const bf16* __restrict__ BT, const bf16* __restrict__ BT2, int ldb,
    const float* __restrict__ bias1, const float* __restrict__ bias2,
    int K, int NB,
    const float* __restrict__ res, const float* __restrict__ gate,
    void* __restrict__ outp, int ldo)
{
  alignas(16) __shared__ short As[128*32];
  alignas(16) __shared__ short Bs[128*32];
  alignas(16) __shared__ short Bs2[(MODE==3)? 128*32 : 8];

  int tid = threadIdx.x;
  int lane = tid & 63, wid = tid >> 6;
  int wm = wid >> 1, wn = wid & 1;
  int l15 = lane & 15, l4 = lane >> 4;
  int brow = blockIdx.x * 128;
  int bcol = blockIdx.y * 128;

  // staging geometry: thread t covers LDS bytes [t*16, t*16+16) of the 8KB tile,
  // i.e. row = t>>2, k-offset = (t&3)*8 elements; two chunks (t, t+256).
  int sr0 = tid >> 2,        sk0 = (tid & 3) * 8;
  int sr1 = (tid+256) >> 2,  sk1 = sk0;

  f32x4 zero4 = {0.f,0.f,0.f,0.f};
  f32x4 acc[4][4], acc2[4][4];
  #pragma unroll
  for(int m=0;m<4;++m)
    #pragma unroll
    for(int n=0;n<4;++n){ acc[m][n]=zero4; acc2[m][n]=zero4; }

  const bf16* a0 = A  + (size_t)(brow+sr0)*lda + sk0;
  const bf16* a1 = A  + (size_t)(brow+sr1)*lda + sk1;
  const bf16* b0 = BT + (size_t)(bcol+sr0)*ldb + sk0;
  const bf16* b1 = BT + (size_t)(bcol+sr1)*ldb + sk1;
  const bf16* c0 = (MODE==3) ? BT2 + (size_t)(bcol+sr0)*ldb + sk0 : nullptr;
  const bf16* c1 = (MODE==3) ? BT2 + (size_t)(bcol+sr1)*ldb + sk1 : nullptr;

  const int nk = K >> 5;
  for(int kt=0; kt<nk; ++kt){
    __syncthreads();
    int ko = kt << 5;
    gload16(a0 + ko, &As[tid*8]);
    gload16(a1 + ko, &As[(tid+256)*8]);
    gload16(b0 + ko, &Bs[tid*8]);
    gload16(b1 + ko, &Bs[(tid+256)*8]);
    if constexpr (MODE==3){
      gload16(c0 + ko, &Bs2[tid*8]);
      gload16(c1 + ko, &Bs2[(tid+256)*8]);
    }
    __syncthreads();   // compiler emits s_waitcnt vmcnt(0) before s_barrier

    bf16x8 af[4], bfr[4], bfr2[4];
    #pragma unroll
    for(int m=0;m<4;++m) af[m] = *(const bf16x8*)&As[(wm*64 + m*16 + l15)*32 + l4*8];
    #pragma unroll
    for(int n=0;n<4;++n) bfr[n] = *(const bf16x8*)&Bs[(wn*64 + n*16 + l15)*32 + l4*8];
    if constexpr (MODE==3){
      #pragma unroll
      for(int n=0;n<4;++n) bfr2[n] = *(const bf16x8*)&Bs2[(wn*64 + n*16 + l15)*32 + l4*8];
    }
    #pragma unroll
    for(int m=0;m<4;++m){
      #pragma unroll
      for(int n=0;n<4;++n){
        acc[m][n] = mfma16(af[m], bfr[n], acc[m][n]);
        if constexpr (MODE==3) acc2[m][n] = mfma16(af[m], bfr2[n], acc2[m][n]);
      }
    }
  }

  // epilogue: C layout col=lane&15, row=(lane>>4)*4+j  [guide-verified]
  #pragma unroll
  for(int m=0;m<4;++m){
    #pragma unroll
    for(int n=0;n<4;++n){
      #pragma unroll
      for(int j=0;j<4;++j){
        int r  = brow + wm*64 + m*16 + l4*4 + j;
        int cc = bcol + wn*64 + n*16 + l15;
        float v = acc[m][n][j];
        if constexpr (MODE==0){
          v += bias1[cc];
          ((bf16*)outp)[(size_t)r*ldo + cc] = f2bf(v);
        } else if constexpr (MODE==1 || MODE==2){
          v += bias1[cc];
          int b = r >> 10;
          float xr = res[(size_t)r*Dd + cc];
          ((float*)outp)[(size_t)r*ldo + cc] = xr + gate[(size_t)b*ADA_LD + cc]*v;
        } else {
          if(cc < MLPH_PAD){
            float o = 0.f;
            if(cc < MLPH){
              float v1 = v + bias1[cc];
              float v2 = acc2[m][n][j] + bias2[cc];
              o = (v1/(1.f+__expf(-v1)))*v2;
            }
            ((bf16*)outp)[(size_t)r*ldo + cc] = f2bf(o);
          }
        }
      }
    }
  }
}

// ---------------- flash attention, per (b,h) and 64-row Q block ----------------
__global__ __launch_bounds__(256) void k_attn(const bf16* __restrict__ qkv, bf16* __restrict__ obuf){
  constexpr int LT = 72;  // 144B rows: 16B-aligned b128, 2-way banks
  alignas(16) __shared__ short Qs[64*LT];
  alignas(16) __shared__ short Ks[64*LT];
  alignas(16) __shared__ short VTs[64*LT];  // [hd][s']
  alignas(16) __shared__ short Ps[64*LT];

  int bh = blockIdx.x;
  int b = bh >> 4, h = bh & 15;
  int qb = blockIdx.y;
  int tid = threadIdx.x;
  int lane = tid & 63, w = tid >> 6;
  int l15 = lane & 15, l4 = lane >> 4;

  const bf16* base = qkv + (size_t)b*Ss*3072 + h*HD;

  #pragma unroll
  for(int ch=0; ch<2; ++ch){
    int flat = (tid + ch*256)*8;
    int row = flat >> 6, col = flat & 63;
    bf16x8 v = *(const bf16x8*)(base + (size_t)(qb*64+row)*3072 + col);
    *(bf16x8*)&Qs[row*LT + col] = v;
  }

  f32x4 zero4 = {0.f,0.f,0.f,0.f};
  f32x4 acc_o[4];
  #pragma unroll
  for(int i=0;i<4;++i) acc_o[i] = zero4;
  float mrow[4], lrow[4];
  #pragma unroll
  for(int j=0;j<4;++j){ mrow[j] = -1e30f; lrow[j] = 0.f; }

  for(int kb=0; kb<Ss/64; ++kb){
    __syncthreads();
    #pragma unroll
    for(int ch=0; ch<2; ++ch){
      int flat = (tid + ch*256)*8;
      int row = flat >> 6, col = flat & 63;
      bf16x8 kv = *(const bf16x8*)(base + Dd + (size_t)(kb*64+row)*3072 + col);
      *(bf16x8*)&Ks[row*LT + col] = kv;
      bf16x8 vv = *(const bf16x8*)(base + 2*Dd + (size_t)(kb*64+row)*3072 + col);
      #pragma unroll
      for(int i=0;i<8;++i) VTs[(col+i)*LT + row] = vv[i];
    }
    __syncthreads();

    // QK^T: wave w owns Q rows w*16..w*16+15, all 64 K cols
    f32x4 sacc[4];
    #pragma unroll
    for(int an=0;an<4;++an) sacc[an]=zero4;
    bf16x8 aq0 = *(const bf16x8*)&Qs[(w*16+l15)*LT + l4*8];
    bf16x8 aq1 = *(const bf16x8*)&Qs[(w*16+l15)*LT + 32 + l4*8];
    #pragma unroll
    for(int an=0;an<4;++an){
      bf16x8 bk0 = *(const bf16x8*)&Ks[(an*16+l15)*LT + l4*8];
      bf16x8 bk1 = *(const bf16x8*)&Ks[(an*16+l15)*LT + 32 + l4*8];
      sacc[an] = mfma16(aq0, bk0, sacc[an]);
      sacc[an] = mfma16(aq1, bk1, sacc[an]);
    }
    const float scale = 0.125f;
    #pragma unroll
    for(int j=0;j<4;++j){
      float mx = -1e30f;
      #pragma unroll
      for(int an=0;an<4;++an){ sacc[an][j] *= scale; mx = fmaxf(mx, sacc[an][j]); }
      #pragma unroll
      for(int msk=1;msk<16;msk<<=1) mx = fmaxf(mx, __shfl_xor(mx, msk));
      float mnew = fmaxf(mrow[j], mx);
      float corr = __expf(mrow[j] - mnew);
      mrow[j] = mnew;
      float psum = 0.f;
      #pragma unroll
      for(int an=0;an<4;++an){
        float p = __expf(sacc[an][j] - mnew);
        sacc[an][j] = p;
        psum += p;
      }
      #pragma unroll
      for(int msk=1;msk<16;msk<<=1) psum += __shfl_xor(psum, msk);
      lrow[j] = lrow[j]*corr + psum;
      #pragma unroll
      for(int an=0;an<4;++an) acc_o[an][j] *= corr;
    }
    // P -> LDS (wave-private rows; within-wave write->read through same array)
    #pragma unroll
    for(int an=0;an<4;++an)
      #pragma unroll
      for(int j=0;j<4;++j)
        Ps[(w*16 + l4*4 + j)*LT + an*16 + l15] = f2bfs(sacc[an][j]);
    bf16x8 pa0 = *(const bf16x8*)&Ps[(w*16+l15)*LT + l4*8];
    bf16x8 pa1 = *(const bf16x8*)&Ps[(w*16+l15)*LT + 32 + l4*8];
    #pragma unroll
    for(int an2=0;an2<4;++an2){
      bf16x8 bv0 = *(const bf16x8*)&VTs[(an2*16+l15)*LT + l4*8];
      bf16x8 bv1 = *(const bf16x8*)&VTs[(an2*16+l15)*LT + 32 + l4*8];
      acc_o[an2] = mfma16(pa0, bv0, acc_o[an2]);
      acc_o[an2] = mfma16(pa1, bv1, acc_o[an2]);
    }
  }
  #pragma unroll
  for(int an2=0;an2<4;++an2)
    #pragma unroll
    for(int j=0;j<4;++j){
      int r = qb*64 + w*16 + l4*4 + j;
      float ov = acc_o[an2][j] / lrow[j];
      obuf[((size_t)b*Ss + r)*Dd + h*HD + an2*16 + l15] = f2bf(ov);
    }
}

} // namespace

extern "C" void kernel_launch(void* const* d_in, const int* in_sizes, int n_in,
                              void* d_out, int out_size, void* d_ws, size_t ws_size,
                              hipStream_t stream){
  const float* x      = (const float*)d_in[0];
  const float* c      = (const float*)d_in[1];
  const float* w_qkv  = (const float*)d_in[2];
  const float* b_qkv  = (const float*)d_in[3];
  const float* w_proj = (const float*)d_in[4];
  const float* b_proj = (const float*)d_in[5];
  const float* w12    = (const float*)d_in[6];
  const float* b12    = (const float*)d_in[7];
  const float* w3     = (const float*)d_in[8];
  const float* b3     = (const float*)d_in[9];
  const float* w_ada  = (const float*)d_in[10];
  const float* b_ada  = (const float*)d_in[11];
  const float* n1w    = (const float*)d_in[12];
  const float* n2w    = (const float*)d_in[13];
  const float* qnw    = (const float*)d_in[14];
  const float* knw    = (const float*)d_in[15];
  float* out = (float*)d_out;
  (void)in_sizes; (void)n_in; (void)out_size;

  constexpr size_t WS_NEED = 227254272ull;
  if (ws_size < WS_NEED) return;

  char* ws = (char*)d_ws;
  float*  silu_c = (float*)(ws + 0);            //  64 KiB  f32 [16,1024]
  float*  ada    = (float*)(ws + 65536);        // 384 KiB  f32 [16,6144]
  float2* ropet  = (float2*)(ws + 458752);      // 256 KiB  [1024,32]
  bf16*   wqkvT  = (bf16*)(ws + 720896);        //   6 MiB  [3072,1024]
  bf16*   wprojT = (bf16*)(ws + 7012352);       //   2 MiB  [1024,1024]
  bf16*   w12T   = (bf16*)(ws + 9109504);       //  10.7MiB [5460,1024]
  bf16*   w3T    = (bf16*)(ws + 20291584);      //   5.4MiB [1024,2752] zero-padded
  bf16*   hbuf   = (bf16*)(ws + 25927680);      //  32 MiB  [16384,1024]
  bf16*   qkvb   = (bf16*)(ws + 59482112);      //  96 MiB  [16384,3072]
  float*  xmid   = (float*)(ws + 160145408);    //  64 MiB  [16384,1024] f32
  bf16*   obuf   = hbuf;   // hbuf dead after QKV GEMM
  bf16*   h2     = hbuf;   // obuf dead after proj GEMM
  bf16*   mlpmid = qkvb;   // qkv dead after attention

  k_silu<<<64,256,0,stream>>>(c, silu_c, Bb*Dd);
  k_rope_tab<<<128,256,0,stream>>>(ropet);
  k_ada<<<24,256,0,stream>>>(silu_c, w_ada, b_ada, ada);
  k_transpose<<<dim3(32,96),256,0,stream>>>(w_qkv, wqkvT, 1024, 3072, 1024);
  k_transpose<<<dim3(32,32),256,0,stream>>>(w_proj, wprojT, 1024, 1024, 1024);
  k_transpose<<<dim3(32,171),256,0,stream>>>(w12, w12T, 1024, 5460, 1024);
  k_transpose<<<dim3(86,32),256,0,stream>>>(w3, w3T, 2730, 1024, 2752);

  // attention branch
  k_norm_mod<<<NR,256,0,stream>>>(x, n1w, ada + 0, ada + 1024, hbuf);
  k_gemm<0><<<dim3(128,24),256,0,stream>>>(hbuf,1024, wqkvT,nullptr,1024,
      b_qkv,nullptr, 1024,0, nullptr,nullptr, qkvb,3072);
  k_qknorm<<<131072,256,0,stream>>>(qkvb, qnw, knw, ropet);
  k_attn<<<dim3(256,16),256,0,stream>>>(qkvb, obuf);
  k_gemm<1><<<dim3(128,8),256,0,stream>>>(obuf,1024, wprojT,nullptr,1024,
      b_proj,nullptr, 1024,0, x, ada + 2048, xmid,1024);

  // MLP branch
  k_norm_mod<<<NR,256,0,stream>>>(xmid, n2w, ada + 3072, ada + 4096, h2);
  k_gemm<3><<<dim3(128,22),256,0,stream>>>(h2,1024, w12T, w12T + (size_t)MLPH*1024, 1024,
      b12, b12 + MLPH, 1024, MLPH, nullptr,nullptr, mlpmid, MLPH_PAD);
  k_gemm<2><<<dim3(128,8),256,0,stream>>>(mlpmid,MLPH_PAD, w3T,nullptr,MLPH_PAD,
      b3,nullptr, MLPH_PAD,0, xmid, ada + 5120, out,1024);
}

// Round 5
// 1572.585 us; speedup vs baseline: 1.1097x; 1.0631x over previous
//
#include <hip/hip_runtime.h>
#include <hip/hip_bf16.h>
#include <math.h>

namespace {

constexpr int Bb = 16;
constexpr int Ss = 1024;
constexpr int Dd = 1024;
constexpr int Hh = 16;
constexpr int HD = 64;
constexpr int MLPH = 2730;
constexpr int MLPH_PAD = 2752;
constexpr int ADA_LD = 6144;
constexpr int NR = Bb * Ss; // 16384 rows

typedef __attribute__((ext_vector_type(8))) short bf16x8;
typedef __attribute__((ext_vector_type(4))) float f32x4;
typedef __hip_bfloat16 bf16;
typedef unsigned int u32;

__device__ __forceinline__ float bf2f(bf16 v){ return __bfloat162float(v); }
__device__ __forceinline__ bf16 f2bf(float v){ return __float2bfloat16(v); }
__device__ __forceinline__ short f2bfs(float v){ bf16 t = __float2bfloat16(v); return __builtin_bit_cast(short, t); }

__device__ __forceinline__ f32x4 mfma16(bf16x8 a, bf16x8 b, f32x4 c){
  return __builtin_amdgcn_mfma_f32_16x16x32_bf16(a, b, c, 0, 0, 0);
}

// async global->LDS, 16B per lane; LDS dest linear (wave base + lane*16)
__device__ __forceinline__ void gload16(const void* g, void* l){
  __builtin_amdgcn_global_load_lds(
      (const __attribute__((address_space(1))) u32*)g,
      (__attribute__((address_space(3))) u32*)l, 16, 0, 0);
}

// ---------------- small kernels ----------------

__global__ void k_silu(const float* __restrict__ c, float* __restrict__ out, int n){
  int i = blockIdx.x*256 + threadIdx.x;
  if(i < n){ float v = c[i]; out[i] = v / (1.f + __expf(-v)); }
}

__global__ __launch_bounds__(256) void k_ada(const float* __restrict__ sc,
    const float* __restrict__ w, const float* __restrict__ bias, float* __restrict__ ada){
  int j = blockIdx.x*256 + threadIdx.x;   // 0..6143
  float acc[Bb];
  #pragma unroll
  for(int b=0;b<Bb;++b) acc[b] = 0.f;
  for(int k=0;k<Dd;++k){
    float wv = w[(size_t)k*ADA_LD + j];
    #pragma unroll
    for(int b=0;b<Bb;++b) acc[b] += sc[b*Dd + k] * wv;
  }
  float bv = bias[j];
  #pragma unroll
  for(int b=0;b<Bb;++b) ada[(size_t)b*ADA_LD + j] = acc[b] + bv;
}

__global__ void k_rope_tab(float2* __restrict__ tab){
  int i = blockIdx.x*256 + threadIdx.x;   // 0..32767 ; i = s*32 + f
  int s = i >> 5, f = i & 31;
  float inv = powf(10000.f, -((float)(2*f)) / 64.f);
  float fr = (float)s * inv;
  float sv, cv;
  sincosf(fr, &sv, &cv);
  tab[i] = make_float2(cv, sv);
}

// in f32 [R,C] -> out bf16 [C,Rpad], zero-filled for col in [R,Rpad)
__global__ void k_transpose(const float* __restrict__ in, bf16* __restrict__ out,
                            int R, int C, int Rpad){
  __shared__ short tile[32][33];
  int tx = threadIdx.x & 31, ty = threadIdx.x >> 5;
  int tr0 = blockIdx.x*32, tc0 = blockIdx.y*32;
  #pragma unroll
  for(int i=0;i<4;++i){
    int r = tr0 + ty + i*8, cc = tc0 + tx;
    short v = 0;
    if(r < R && cc < C) v = f2bfs(in[(size_t)r*C + cc]);
    tile[ty+i*8][tx] = v;
  }
  __syncthreads();
  #pragma unroll
  for(int i=0;i<4;++i){
    int oc = tc0 + ty + i*8;   // out row (former col)
    int orow = tr0 + tx;       // out col (former row)
    if(oc < C && orow < Rpad)
      out[(size_t)oc*Rpad + orow] = __builtin_bit_cast(bf16, tile[tx][ty+i*8]);
  }
}

// RMSNorm over D + adaLN modulate
__global__ __launch_bounds__(256) void k_norm_mod(const float* __restrict__ x,
    const float* __restrict__ w, const float* __restrict__ shift, const float* __restrict__ scale,
    bf16* __restrict__ out){
  int r = blockIdx.x;
  int b = r >> 10;
  int t = threadIdx.x;
  const float* xr = x + (size_t)r*Dd;
  float v[4]; float ss = 0.f;
  #pragma unroll
  for(int i=0;i<4;++i){
    float f = xr[t*4+i];
    v[i] = f; ss += f*f;
  }
  #pragma unroll
  for(int m=1;m<64;m<<=1) ss += __shfl_xor(ss, m);
  __shared__ float red[4];
  if((t & 63) == 0) red[t>>6] = ss;
  __syncthreads();
  float tot = red[0]+red[1]+red[2]+red[3];
  float rms = rsqrtf(tot * (1.f/Dd) + 1e-6f);
  #pragma unroll
  for(int i=0;i<4;++i){
    int ccol = t*4+i;
    float h = v[i]*rms*w[ccol];
    float scv = scale[(size_t)b*ADA_LD + ccol];
    float shv = shift[(size_t)b*ADA_LD + ccol];
    out[(size_t)r*Dd + ccol] = f2bf(h*(1.f+scv) + shv);
  }
}

// per-(b,s,h) RMSNorm(64) + RoPE for q and k rows of qkv, in place
__global__ __launch_bounds__(256) void k_qknorm(bf16* __restrict__ qkv,
    const float* __restrict__ qw, const float* __restrict__ kw, const float2* __restrict__ tab){
  int gid = blockIdx.x*256 + threadIdx.x;
  int lane = gid & 63;
  int wid = gid >> 6;          // 0 .. 524287
  int isK = wid & 1;
  int bsh = wid >> 1;          // 0 .. 262143
  int h = bsh & (Hh-1);
  int bs = bsh >> 4;           // 0..16383
  int s = bs & (Ss-1);
  bf16* p = qkv + (size_t)bs*3072 + isK*Dd + h*HD + lane;
  float vv = bf2f(*p);
  float ss = vv*vv;
  #pragma unroll
  for(int m=1;m<64;m<<=1) ss += __shfl_xor(ss, m);
  float rms = rsqrtf(ss*(1.f/HD) + 1e-6f);
  const float* wn = isK ? kw : qw;
  float xn = vv*rms*wn[lane];
  float other = __shfl_xor(xn, 32);
  float2 cs = tab[s*32 + (lane & 31)];
  float o = (lane < 32) ? (xn*cs.x - other*cs.y) : (other*cs.y + xn*cs.x);
  *p = f2bf(o);
}

// ---------------- GEMM: C[M,N] = A[M,K] * BT[N,K]^T (+ epilogues) ----------------
// 2-phase double-buffered: STAGE(t+1) issued BEFORE compute of t; one
// __syncthreads (vmcnt0+lgkmcnt0 drain) per K-step. LDS k-chunk slot is
// XOR-swizzled (slot = k8 ^ ((row>>1)&3)) via pre-swizzled GLOBAL source
// (LDS dest stays linear for global_load_lds) + same XOR on ds_read side.
// MODE 0: out bf16 = acc + bias1[n]
// MODE 1/2: out f32 = res[r,n] + gate[b,n]*(acc + bias1[n])
// MODE 3: dual-B swiglu: out bf16 = silu(acc1+bias1[n]) * (acc2+bias2[n]); n>=MLPH -> 0
template<int MODE>
__global__ __launch_bounds__(256) void k_gemm(
    const bf16* __restrict__ A, int lda,
    const bf16* __restrict__ BT, const bf16* __restrict__ BT2, int ldb,
    const float* __restrict__ bias1, const float* __restrict__ bias2,
    int K, int NB,
    const float* __restrict__ res, const float* __restrict__ gate,
    void* __restrict__ outp, int ldo)
{
  alignas(16) __shared__ short As[2][128*32];
  alignas(16) __shared__ short Bs[2][128*32];
  alignas(16) __shared__ short Bs2[(MODE==3)?2:1][(MODE==3)?128*32:8];

  int tid = threadIdx.x;
  int lane = tid & 63, wid = tid >> 6;
  int wm = wid >> 1, wn = wid & 1;
  int l15 = lane & 15, l4 = lane >> 4;
  int brow = blockIdx.x * 128;
  int bcol = blockIdx.y * 128;

  // staging: thread t owns linear LDS slot t (row=t>>2, s=t&3); its global
  // source is k-chunk k8 = s ^ ((row>>1)&3)  [swizzle involution]
  int r0 = tid >> 2,        s0 = tid & 3;
  int r1 = (tid+256) >> 2;
  int k80 = s0 ^ ((r0 >> 1) & 3);
  int k81 = s0 ^ ((r1 >> 1) & 3);

  const bf16* a0 = A  + (size_t)(brow+r0)*lda + k80*8;
  const bf16* a1 = A  + (size_t)(brow+r1)*lda + k81*8;
  const bf16* b0 = BT + (size_t)(bcol+r0)*ldb + k80*8;
  const bf16* b1 = BT + (size_t)(bcol+r1)*ldb + k81*8;
  const bf16* c0 = (MODE==3) ? BT2 + (size_t)(bcol+r0)*ldb + k80*8 : nullptr;
  const bf16* c1 = (MODE==3) ? BT2 + (size_t)(bcol+r1)*ldb + k81*8 : nullptr;

  f32x4 zero4 = {0.f,0.f,0.f,0.f};
  f32x4 acc[4][4], acc2[4][4];
  #pragma unroll
  for(int m=0;m<4;++m)
    #pragma unroll
    for(int n=0;n<4;++n){ acc[m][n]=zero4; acc2[m][n]=zero4; }

  auto STAGE = [&](int kt, int buf){
    int ko = kt << 5;
    gload16(a0 + ko, &As[buf][tid*8]);
    gload16(a1 + ko, &As[buf][(tid+256)*8]);
    gload16(b0 + ko, &Bs[buf][tid*8]);
    gload16(b1 + ko, &Bs[buf][(tid+256)*8]);
    if constexpr (MODE==3){
      gload16(c0 + ko, &Bs2[buf][tid*8]);
      gload16(c1 + ko, &Bs2[buf][(tid+256)*8]);
    }
  };

  const int nk = K >> 5;
  STAGE(0, 0);
  __syncthreads();          // drain prologue loads

  int cur = 0;
  for(int kt=0; kt<nk; ++kt){
    if(kt+1 < nk) STAGE(kt+1, cur^1);   // prefetch next tile (other buffer)

    bf16x8 af[4], bfr[4], bfr2[4];
    #pragma unroll
    for(int m=0;m<4;++m){
      int rr = wm*64 + m*16 + l15;
      int sl = l4 ^ ((rr >> 1) & 3);
      af[m] = *(const bf16x8*)&As[cur][rr*32 + sl*8];
    }
    #pragma unroll
    for(int n=0;n<4;++n){
      int rr = wn*64 + n*16 + l15;
      int sl = l4 ^ ((rr >> 1) & 3);
      bfr[n] = *(const bf16x8*)&Bs[cur][rr*32 + sl*8];
      if constexpr (MODE==3)
        bfr2[n] = *(const bf16x8*)&Bs2[cur][rr*32 + sl*8];
    }
    #pragma unroll
    for(int m=0;m<4;++m){
      #pragma unroll
      for(int n=0;n<4;++n){
        acc[m][n] = mfma16(af[m], bfr[n], acc[m][n]);
        if constexpr (MODE==3) acc2[m][n] = mfma16(af[m], bfr2[n], acc2[m][n]);
      }
    }
    __syncthreads();        // drains prefetch (vmcnt0) + guards buffer reuse
    cur ^= 1;
  }

  // epilogue: C layout col=lane&15, row=(lane>>4)*4+j  [guide-verified]
  #pragma unroll
  for(int m=0;m<4;++m){
    #pragma unroll
    for(int n=0;n<4;++n){
      #pragma unroll
      for(int j=0;j<4;++j){
        int r  = brow + wm*64 + m*16 + l4*4 + j;
        int cc = bcol + wn*64 + n*16 + l15;
        float v = acc[m][n][j];
        if constexpr (MODE==0){
          v += bias1[cc];
          ((bf16*)outp)[(size_t)r*ldo + cc] = f2bf(v);
        } else if constexpr (MODE==1 || MODE==2){
          v += bias1[cc];
          int b = r >> 10;
          float xr = res[(size_t)r*Dd + cc];
          ((float*)outp)[(size_t)r*ldo + cc] = xr + gate[(size_t)b*ADA_LD + cc]*v;
        } else {
          if(cc < MLPH_PAD){
            float o = 0.f;
            if(cc < MLPH){
              float v1 = v + bias1[cc];
              float v2 = acc2[m][n][j] + bias2[cc];
              o = (v1/(1.f+__expf(-v1)))*v2;
            }
            ((bf16*)outp)[(size_t)r*ldo + cc] = f2bf(o);
          }
        }
      }
    }
  }
}

// ---------------- flash attention, per (b,h) and 64-row Q block ----------------
__global__ __launch_bounds__(256) void k_attn(const bf16* __restrict__ qkv, bf16* __restrict__ obuf){
  constexpr int LT = 72;  // 144B rows: 16B-aligned b128, 2-way banks
  alignas(16) __shared__ short Qs[64*LT];
  alignas(16) __shared__ short Ks[64*LT];
  alignas(16) __shared__ short VTs[64*LT];  // [hd][s']
  alignas(16) __shared__ short Ps[64*LT];

  int bh = blockIdx.x;
  int b = bh >> 4, h = bh & 15;
  int qb = blockIdx.y;
  int tid = threadIdx.x;
  int lane = tid & 63, w = tid >> 6;
  int l15 = lane & 15, l4 = lane >> 4;

  const bf16* base = qkv + (size_t)b*Ss*3072 + h*HD;

  #pragma unroll
  for(int ch=0; ch<2; ++ch){
    int flat = (tid + ch*256)*8;
    int row = flat >> 6, col = flat & 63;
    bf16x8 v = *(const bf16x8*)(base + (size_t)(qb*64+row)*3072 + col);
    *(bf16x8*)&Qs[row*LT + col] = v;
  }

  f32x4 zero4 = {0.f,0.f,0.f,0.f};
  f32x4 acc_o[4];
  #pragma unroll
  for(int i=0;i<4;++i) acc_o[i] = zero4;
  float mrow[4], lrow[4];
  #pragma unroll
  for(int j=0;j<4;++j){ mrow[j] = -1e30f; lrow[j] = 0.f; }

  for(int kb=0; kb<Ss/64; ++kb){
    __syncthreads();
    #pragma unroll
    for(int ch=0; ch<2; ++ch){
      int flat = (tid + ch*256)*8;
      int row = flat >> 6, col = flat & 63;
      bf16x8 kv = *(const bf16x8*)(base + Dd + (size_t)(kb*64+row)*3072 + col);
      *(bf16x8*)&Ks[row*LT + col] = kv;
      bf16x8 vv = *(const bf16x8*)(base + 2*Dd + (size_t)(kb*64+row)*3072 + col);
      #pragma unroll
      for(int i=0;i<8;++i) VTs[(col+i)*LT + row] = vv[i];
    }
    __syncthreads();

    // QK^T: wave w owns Q rows w*16..w*16+15, all 64 K cols
    f32x4 sacc[4];
    #pragma unroll
    for(int an=0;an<4;++an) sacc[an]=zero4;
    bf16x8 aq0 = *(const bf16x8*)&Qs[(w*16+l15)*LT + l4*8];
    bf16x8 aq1 = *(const bf16x8*)&Qs[(w*16+l15)*LT + 32 + l4*8];
    #pragma unroll
    for(int an=0;an<4;++an){
      bf16x8 bk0 = *(const bf16x8*)&Ks[(an*16+l15)*LT + l4*8];
      bf16x8 bk1 = *(const bf16x8*)&Ks[(an*16+l15)*LT + 32 + l4*8];
      sacc[an] = mfma16(aq0, bk0, sacc[an]);
      sacc[an] = mfma16(aq1, bk1, sacc[an]);
    }
    const float scale = 0.125f;
    #pragma unroll
    for(int j=0;j<4;++j){
      float mx = -1e30f;
      #pragma unroll
      for(int an=0;an<4;++an){ sacc[an][j] *= scale; mx = fmaxf(mx, sacc[an][j]); }
      #pragma unroll
      for(int msk=1;msk<16;msk<<=1) mx = fmaxf(mx, __shfl_xor(mx, msk));
      float mnew = fmaxf(mrow[j], mx);
      float corr = __expf(mrow[j] - mnew);
      mrow[j] = mnew;
      float psum = 0.f;
      #pragma unroll
      for(int an=0;an<4;++an){
        float p = __expf(sacc[an][j] - mnew);
        sacc[an][j] = p;
        psum += p;
      }
      #pragma unroll
      for(int msk=1;msk<16;msk<<=1) psum += __shfl_xor(psum, msk);
      lrow[j] = lrow[j]*corr + psum;
      #pragma unroll
      for(int an=0;an<4;++an) acc_o[an][j] *= corr;
    }
    // P -> LDS (wave-private rows; within-wave write->read through same array)
    #pragma unroll
    for(int an=0;an<4;++an)
      #pragma unroll
      for(int j=0;j<4;++j)
        Ps[(w*16 + l4*4 + j)*LT + an*16 + l15] = f2bfs(sacc[an][j]);
    bf16x8 pa0 = *(const bf16x8*)&Ps[(w*16+l15)*LT + l4*8];
    bf16x8 pa1 = *(const bf16x8*)&Ps[(w*16+l15)*LT + 32 + l4*8];
    #pragma unroll
    for(int an2=0;an2<4;++an2){
      bf16x8 bv0 = *(const bf16x8*)&VTs[(an2*16+l15)*LT + l4*8];
      bf16x8 bv1 = *(const bf16x8*)&VTs[(an2*16+l15)*LT + 32 + l4*8];
      acc_o[an2] = mfma16(pa0, bv0, acc_o[an2]);
      acc_o[an2] = mfma16(pa1, bv1, acc_o[an2]);
    }
  }
  #pragma unroll
  for(int an2=0;an2<4;++an2)
    #pragma unroll
    for(int j=0;j<4;++j){
      int r = qb*64 + w*16 + l4*4 + j;
      float ov = acc_o[an2][j] / lrow[j];
      obuf[((size_t)b*Ss + r)*Dd + h*HD + an2*16 + l15] = f2bf(ov);
    }
}

} // namespace

extern "C" void kernel_launch(void* const* d_in, const int* in_sizes, int n_in,
                              void* d_out, int out_size, void* d_ws, size_t ws_size,
                              hipStream_t stream){
  const float* x      = (const float*)d_in[0];
  const float* c      = (const float*)d_in[1];
  const float* w_qkv  = (const float*)d_in[2];
  const float* b_qkv  = (const float*)d_in[3];
  const float* w_proj = (const float*)d_in[4];
  const float* b_proj = (const float*)d_in[5];
  const float* w12    = (const float*)d_in[6];
  const float* b12    = (const float*)d_in[7];
  const float* w3     = (const float*)d_in[8];
  const float* b3     = (const float*)d_in[9];
  const float* w_ada  = (const float*)d_in[10];
  const float* b_ada  = (const float*)d_in[11];
  const float* n1w    = (const float*)d_in[12];
  const float* n2w    = (const float*)d_in[13];
  const float* qnw    = (const float*)d_in[14];
  const float* knw    = (const float*)d_in[15];
  float* out = (float*)d_out;
  (void)in_sizes; (void)n_in; (void)out_size;

  constexpr size_t WS_NEED = 227254272ull;
  if (ws_size < WS_NEED) return;

  char* ws = (char*)d_ws;
  float*  silu_c = (float*)(ws + 0);            //  64 KiB  f32 [16,1024]
  float*  ada    = (float*)(ws + 65536);        // 384 KiB  f32 [16,6144]
  float2* ropet  = (float2*)(ws + 458752);      // 256 KiB  [1024,32]
  bf16*   wqkvT  = (bf16*)(ws + 720896);        //   6 MiB  [3072,1024]
  bf16*   wprojT = (bf16*)(ws + 7012352);       //   2 MiB  [1024,1024]
  bf16*   w12T   = (bf16*)(ws + 9109504);       //  10.7MiB [5460,1024]
  bf16*   w3T    = (bf16*)(ws + 20291584);      //   5.4MiB [1024,2752] zero-padded
  bf16*   hbuf   = (bf16*)(ws + 25927680);      //  32 MiB  [16384,1024]
  bf16*   qkvb   = (bf16*)(ws + 59482112);      //  96 MiB  [16384,3072]
  float*  xmid   = (float*)(ws + 160145408);    //  64 MiB  [16384,1024] f32
  bf16*   obuf   = hbuf;   // hbuf dead after QKV GEMM
  bf16*   h2     = hbuf;   // obuf dead after proj GEMM
  bf16*   mlpmid = qkvb;   // qkv dead after attention

  k_silu<<<64,256,0,stream>>>(c, silu_c, Bb*Dd);
  k_rope_tab<<<128,256,0,stream>>>(ropet);
  k_ada<<<24,256,0,stream>>>(silu_c, w_ada, b_ada, ada);
  k_transpose<<<dim3(32,96),256,0,stream>>>(w_qkv, wqkvT, 1024, 3072, 1024);
  k_transpose<<<dim3(32,32),256,0,stream>>>(w_proj, wprojT, 1024, 1024, 1024);
  k_transpose<<<dim3(32,171),256,0,stream>>>(w12, w12T, 1024, 5460, 1024);
  k_transpose<<<dim3(86,32),256,0,stream>>>(w3, w3T, 2730, 1024, 2752);

  // attention branch
  k_norm_mod<<<NR,256,0,stream>>>(x, n1w, ada + 0, ada + 1024, hbuf);
  k_gemm<0><<<dim3(128,24),256,0,stream>>>(hbuf,1024, wqkvT,nullptr,1024,
      b_qkv,nullptr, 1024,0, nullptr,nullptr, qkvb,3072);
  k_qknorm<<<131072,256,0,stream>>>(qkvb, qnw, knw, ropet);
  k_attn<<<dim3(256,16),256,0,stream>>>(qkvb, obuf);
  k_gemm<1><<<dim3(128,8),256,0,stream>>>(obuf,1024, wprojT,nullptr,1024,
      b_proj,nullptr, 1024,0, x, ada + 2048, xmid,1024);

  // MLP branch
  k_norm_mod<<<NR,256,0,stream>>>(xmid, n2w, ada + 3072, ada + 4096, h2);
  k_gemm<3><<<dim3(128,22),256,0,stream>>>(h2,1024, w12T, w12T + (size_t)MLPH*1024, 1024,
      b12, b12 + MLPH, 1024, MLPH, nullptr,nullptr, mlpmid, MLPH_PAD);
  k_gemm<2><<<dim3(128,8),256,0,stream>>>(mlpmid,MLPH_PAD, w3T,nullptr,MLPH_PAD,
      b3,nullptr, MLPH_PAD,0, xmid, ada + 5120, out,1024);
}

// Round 6
// 1126.361 us; speedup vs baseline: 1.5493x; 1.3962x over previous
//
#include <hip/hip_runtime.h>
#include <hip/hip_bf16.h>
#include <math.h>

namespace {

constexpr int Bb = 16;
constexpr int Ss = 1024;
constexpr int Dd = 1024;
constexpr int Hh = 16;
constexpr int HD = 64;
constexpr int MLPH = 2730;
constexpr int MLPH_PAD = 2752;
constexpr int ADA_LD = 6144;
constexpr int NR = Bb * Ss; // 16384 rows

typedef __attribute__((ext_vector_type(8))) short bf16x8;
typedef __attribute__((ext_vector_type(4))) float f32x4;
typedef __hip_bfloat16 bf16;
typedef unsigned int u32;

__device__ __forceinline__ float bf2f(bf16 v){ return __bfloat162float(v); }
__device__ __forceinline__ bf16 f2bf(float v){ return __float2bfloat16(v); }
__device__ __forceinline__ short f2bfs(float v){ bf16 t = __float2bfloat16(v); return __builtin_bit_cast(short, t); }

__device__ __forceinline__ f32x4 mfma16(bf16x8 a, bf16x8 b, f32x4 c){
  return __builtin_amdgcn_mfma_f32_16x16x32_bf16(a, b, c, 0, 0, 0);
}

// async global->LDS, 16B per lane; LDS dest linear (wave base + lane*16)
__device__ __forceinline__ void gload16(const void* g, void* l){
  __builtin_amdgcn_global_load_lds(
      (const __attribute__((address_space(1))) u32*)g,
      (__attribute__((address_space(3))) u32*)l, 16, 0, 0);
}

// ---------------- small kernels ----------------

__global__ void k_silu(const float* __restrict__ c, float* __restrict__ out, int n){
  int i = blockIdx.x*256 + threadIdx.x;
  if(i < n){ float v = c[i]; out[i] = v / (1.f + __expf(-v)); }
}

// grid 96: each block owns 64 cols of ada; 4-way K-split + LDS reduce
__global__ __launch_bounds__(256) void k_ada(const float* __restrict__ sc,
    const float* __restrict__ w, const float* __restrict__ bias, float* __restrict__ ada){
  __shared__ float red[4][Bb][64];
  int tid = threadIdx.x;
  int jj = tid & 63, ks = tid >> 6;
  int j = blockIdx.x*64 + jj;
  float acc[Bb];
  #pragma unroll
  for(int b=0;b<Bb;++b) acc[b] = 0.f;
  for(int k=ks*256; k<ks*256+256; ++k){
    float wv = w[(size_t)k*ADA_LD + j];
    #pragma unroll
    for(int b=0;b<Bb;++b) acc[b] += sc[b*Dd + k] * wv;
  }
  #pragma unroll
  for(int b=0;b<Bb;++b) red[ks][b][jj] = acc[b];
  __syncthreads();
  #pragma unroll
  for(int rep=0;rep<4;++rep){
    int idx = rep*256 + tid;       // 0..1023
    int b = idx >> 6, j2 = idx & 63;
    float s = red[0][b][j2]+red[1][b][j2]+red[2][b][j2]+red[3][b][j2];
    ada[(size_t)b*ADA_LD + blockIdx.x*64 + j2] = s + bias[blockIdx.x*64 + j2];
  }
}

__global__ void k_rope_tab(float2* __restrict__ tab){
  int i = blockIdx.x*256 + threadIdx.x;   // 0..32767 ; i = s*32 + f
  int s = i >> 5, f = i & 31;
  float inv = powf(10000.f, -((float)(2*f)) / 64.f);
  float fr = (float)s * inv;
  float sv, cv;
  sincosf(fr, &sv, &cv);
  tab[i] = make_float2(cv, sv);
}

// in f32 [R,C] -> out bf16 [C,Rpad], zero-filled for col in [R,Rpad)
__global__ void k_transpose(const float* __restrict__ in, bf16* __restrict__ out,
                            int R, int C, int Rpad){
  __shared__ short tile[32][33];
  int tx = threadIdx.x & 31, ty = threadIdx.x >> 5;
  int tr0 = blockIdx.x*32, tc0 = blockIdx.y*32;
  #pragma unroll
  for(int i=0;i<4;++i){
    int r = tr0 + ty + i*8, cc = tc0 + tx;
    short v = 0;
    if(r < R && cc < C) v = f2bfs(in[(size_t)r*C + cc]);
    tile[ty+i*8][tx] = v;
  }
  __syncthreads();
  #pragma unroll
  for(int i=0;i<4;++i){
    int oc = tc0 + ty + i*8;   // out row (former col)
    int orow = tr0 + tx;       // out col (former row)
    if(oc < C && orow < Rpad)
      out[(size_t)oc*Rpad + orow] = __builtin_bit_cast(bf16, tile[tx][ty+i*8]);
  }
}

// RMSNorm over D + adaLN modulate
__global__ __launch_bounds__(256) void k_norm_mod(const float* __restrict__ x,
    const float* __restrict__ w, const float* __restrict__ shift, const float* __restrict__ scale,
    bf16* __restrict__ out){
  int r = blockIdx.x;
  int b = r >> 10;
  int t = threadIdx.x;
  const float* xr = x + (size_t)r*Dd;
  float v[4]; float ss = 0.f;
  #pragma unroll
  for(int i=0;i<4;++i){
    float f = xr[t*4+i];
    v[i] = f; ss += f*f;
  }
  #pragma unroll
  for(int m=1;m<64;m<<=1) ss += __shfl_xor(ss, m);
  __shared__ float red[4];
  if((t & 63) == 0) red[t>>6] = ss;
  __syncthreads();
  float tot = red[0]+red[1]+red[2]+red[3];
  float rms = rsqrtf(tot * (1.f/Dd) + 1e-6f);
  #pragma unroll
  for(int i=0;i<4;++i){
    int ccol = t*4+i;
    float h = v[i]*rms*w[ccol];
    float scv = scale[(size_t)b*ADA_LD + ccol];
    float shv = shift[(size_t)b*ADA_LD + ccol];
    out[(size_t)r*Dd + ccol] = f2bf(h*(1.f+scv) + shv);
  }
}

// per-(b,s,h) RMSNorm(64) + RoPE for q and k rows of qkv, in place
__global__ __launch_bounds__(256) void k_qknorm(bf16* __restrict__ qkv,
    const float* __restrict__ qw, const float* __restrict__ kw, const float2* __restrict__ tab){
  int gid = blockIdx.x*256 + threadIdx.x;
  int lane = gid & 63;
  int wid = gid >> 6;          // 0 .. 524287
  int isK = wid & 1;
  int bsh = wid >> 1;          // 0 .. 262143
  int h = bsh & (Hh-1);
  int bs = bsh >> 4;           // 0..16383
  int s = bs & (Ss-1);
  bf16* p = qkv + (size_t)bs*3072 + isK*Dd + h*HD + lane;
  float vv = bf2f(*p);
  float ss = vv*vv;
  #pragma unroll
  for(int m=1;m<64;m<<=1) ss += __shfl_xor(ss, m);
  float rms = rsqrtf(ss*(1.f/HD) + 1e-6f);
  const float* wn = isK ? kw : qw;
  float xn = vv*rms*wn[lane];
  float other = __shfl_xor(xn, 32);
  float2 cs = tab[s*32 + (lane & 31)];
  float o = (lane < 32) ? (xn*cs.x - other*cs.y) : (other*cs.y + xn*cs.x);
  *p = f2bf(o);
}

// ---------------- GEMM: C[M,N] = A[M,K] * BT[N,K]^T (+ epilogues) ----------------
// 2-phase dbuf, global_load_lds staging, XOR k-slot swizzle (both sides).
// MODE 0: 128x128 tile; out bf16 = acc + bias1[n]
// MODE 1: 128x128 tile; out f32 = res[r,n] + gate[b,n]*(acc + bias1[n])
// MODE 3: 128x64 tile (dual-acc fits 2 waves/SIMD);
//         out bf16 = silu(acc1+bias1[n]) * (acc2+bias2[n]); n in [MLPH,MLPH_PAD) -> 0
//         B2 row = B row + b2off elements (w12T halves are contiguous)
template<int MODE>
__global__ __launch_bounds__(256, 2) void k_gemm(
    const bf16* __restrict__ A, int lda,
    const bf16* __restrict__ BT, long long b2off, int ldb,
    const float* __restrict__ bias1, const float* __restrict__ bias2,
    int K,
    const float* __restrict__ res, const float* __restrict__ gate,
    void* __restrict__ outp, int ldo)
{
  constexpr int BN  = (MODE==3) ? 64 : 128;   // block N-extent
  constexpr int NFR = (MODE==3) ? 2  : 4;     // B fragments per wave (wave N = 16*NFR)
  alignas(16) __shared__ short As[2][128*32];
  alignas(16) __shared__ short Bs[2][BN*32];
  alignas(16) __shared__ short Bs2[(MODE==3)?2:1][(MODE==3)?BN*32:8];

  int tid = threadIdx.x;
  int lane = tid & 63, wid = tid >> 6;
  int wm = wid >> 1, wn = wid & 1;
  int l15 = lane & 15, l4 = lane >> 4;
  int brow = blockIdx.x * 128;
  int bcol = blockIdx.y * BN;

  // staging: thread t owns linear LDS slot t (row=t>>2, s=t&3); global source
  // k-chunk k8 = s ^ ((row>>1)&3)  [swizzle involution, read side matches]
  int r0 = tid >> 2, s0 = tid & 3;
  int r1 = r0 + 64;
  int k80 = s0 ^ ((r0 >> 1) & 3);
  int k81 = s0 ^ ((r1 >> 1) & 3);

  const bf16* a0 = A  + (size_t)(brow+r0)*lda + k80*8;
  const bf16* a1 = A  + (size_t)(brow+r1)*lda + k81*8;
  const bf16* b0 = BT + (size_t)(bcol+r0)*ldb + k80*8;
  const bf16* b1 = BT + (size_t)(bcol+r1)*ldb + k81*8;  // used only when BN==128

  f32x4 zero4 = {0.f,0.f,0.f,0.f};
  f32x4 acc[4][NFR], acc2[4][NFR];
  #pragma unroll
  for(int m=0;m<4;++m)
    #pragma unroll
    for(int n=0;n<NFR;++n){ acc[m][n]=zero4; acc2[m][n]=zero4; }

  auto STAGE = [&](int kt, int buf){
    int ko = kt << 5;
    gload16(a0 + ko, &As[buf][tid*8]);
    gload16(a1 + ko, &As[buf][(tid+256)*8]);
    gload16(b0 + ko, &Bs[buf][tid*8]);
    if constexpr (MODE!=3) gload16(b1 + ko, &Bs[buf][(tid+256)*8]);
    if constexpr (MODE==3) gload16(b0 + b2off + ko, &Bs2[buf][tid*8]);
  };

  const int nk = K >> 5;
  STAGE(0, 0);
  __syncthreads();

  int cur = 0;
  for(int kt=0; kt<nk; ++kt){
    if(kt+1 < nk) STAGE(kt+1, cur^1);

    bf16x8 af[4], bfr[NFR], bfr2[NFR];
    #pragma unroll
    for(int m=0;m<4;++m){
      int rr = wm*64 + m*16 + l15;
      int sl = l4 ^ ((rr >> 1) & 3);
      af[m] = *(const bf16x8*)&As[cur][rr*32 + sl*8];
    }
    #pragma unroll
    for(int n=0;n<NFR;++n){
      int rr = wn*(16*NFR) + n*16 + l15;
      int sl = l4 ^ ((rr >> 1) & 3);
      bfr[n] = *(const bf16x8*)&Bs[cur][rr*32 + sl*8];
      if constexpr (MODE==3)
        bfr2[n] = *(const bf16x8*)&Bs2[cur][rr*32 + sl*8];
    }
    #pragma unroll
    for(int m=0;m<4;++m){
      #pragma unroll
      for(int n=0;n<NFR;++n){
        acc[m][n] = mfma16(af[m], bfr[n], acc[m][n]);
        if constexpr (MODE==3) acc2[m][n] = mfma16(af[m], bfr2[n], acc2[m][n]);
      }
    }
    __syncthreads();        // drains prefetch (vmcnt0) + guards buffer reuse
    cur ^= 1;
  }

  // epilogue: C layout col=lane&15, row=(lane>>4)*4+j  [guide-verified]
  #pragma unroll
  for(int m=0;m<4;++m){
    #pragma unroll
    for(int n=0;n<NFR;++n){
      #pragma unroll
      for(int j=0;j<4;++j){
        int r  = brow + wm*64 + m*16 + l4*4 + j;
        int cc = bcol + wn*(16*NFR) + n*16 + l15;
        float v = acc[m][n][j];
        if constexpr (MODE==0){
          v += bias1[cc];
          ((bf16*)outp)[(size_t)r*ldo + cc] = f2bf(v);
        } else if constexpr (MODE==1){
          v += bias1[cc];
          int b = r >> 10;
          float xr = res[(size_t)r*Dd + cc];
          ((float*)outp)[(size_t)r*ldo + cc] = xr + gate[(size_t)b*ADA_LD + cc]*v;
        } else {
          float o = 0.f;
          if(cc < MLPH){
            float v1 = v + bias1[cc];
            float v2 = acc2[m][n][j] + bias2[cc];
            o = (v1/(1.f+__expf(-v1)))*v2;
          }
          ((bf16*)outp)[(size_t)r*ldo + cc] = f2bf(o);
        }
      }
    }
  }
}

// ---------------- flash attention, per (b,h) and 64-row Q block ----------------
__global__ __launch_bounds__(256) void k_attn(const bf16* __restrict__ qkv, bf16* __restrict__ obuf){
  constexpr int LT = 72;  // 144B rows: 16B-aligned b128, 2-way banks
  alignas(16) __shared__ short Qs[64*LT];
  alignas(16) __shared__ short Ks[64*LT];
  alignas(16) __shared__ short VTs[64*LT];  // [hd][s']
  alignas(16) __shared__ short Ps[64*LT];

  int bh = blockIdx.x;
  int b = bh >> 4, h = bh & 15;
  int qb = blockIdx.y;
  int tid = threadIdx.x;
  int lane = tid & 63, w = tid >> 6;
  int l15 = lane & 15, l4 = lane >> 4;

  const bf16* base = qkv + (size_t)b*Ss*3072 + h*HD;

  #pragma unroll
  for(int ch=0; ch<2; ++ch){
    int flat = (tid + ch*256)*8;
    int row = flat >> 6, col = flat & 63;
    bf16x8 v = *(const bf16x8*)(base + (size_t)(qb*64+row)*3072 + col);
    *(bf16x8*)&Qs[row*LT + col] = v;
  }

  f32x4 zero4 = {0.f,0.f,0.f,0.f};
  f32x4 acc_o[4];
  #pragma unroll
  for(int i=0;i<4;++i) acc_o[i] = zero4;
  float mrow[4], lrow[4];
  #pragma unroll
  for(int j=0;j<4;++j){ mrow[j] = -1e30f; lrow[j] = 0.f; }

  for(int kb=0; kb<Ss/64; ++kb){
    __syncthreads();
    #pragma unroll
    for(int ch=0; ch<2; ++ch){
      int flat = (tid + ch*256)*8;
      int row = flat >> 6, col = flat & 63;
      bf16x8 kv = *(const bf16x8*)(base + Dd + (size_t)(kb*64+row)*3072 + col);
      *(bf16x8*)&Ks[row*LT + col] = kv;
      bf16x8 vv = *(const bf16x8*)(base + 2*Dd + (size_t)(kb*64+row)*3072 + col);
      #pragma unroll
      for(int i=0;i<8;++i) VTs[(col+i)*LT + row] = vv[i];
    }
    __syncthreads();

    // QK^T: wave w owns Q rows w*16..w*16+15, all 64 K cols
    f32x4 sacc[4];
    #pragma unroll
    for(int an=0;an<4;++an) sacc[an]=zero4;
    bf16x8 aq0 = *(const bf16x8*)&Qs[(w*16+l15)*LT + l4*8];
    bf16x8 aq1 = *(const bf16x8*)&Qs[(w*16+l15)*LT + 32 + l4*8];
    #pragma unroll
    for(int an=0;an<4;++an){
      bf16x8 bk0 = *(const bf16x8*)&Ks[(an*16+l15)*LT + l4*8];
      bf16x8 bk1 = *(const bf16x8*)&Ks[(an*16+l15)*LT + 32 + l4*8];
      sacc[an] = mfma16(aq0, bk0, sacc[an]);
      sacc[an] = mfma16(aq1, bk1, sacc[an]);
    }
    const float scale = 0.125f;
    #pragma unroll
    for(int j=0;j<4;++j){
      float mx = -1e30f;
      #pragma unroll
      for(int an=0;an<4;++an){ sacc[an][j] *= scale; mx = fmaxf(mx, sacc[an][j]); }
      #pragma unroll
      for(int msk=1;msk<16;msk<<=1) mx = fmaxf(mx, __shfl_xor(mx, msk));
      float mnew = fmaxf(mrow[j], mx);
      float corr = __expf(mrow[j] - mnew);
      mrow[j] = mnew;
      float psum = 0.f;
      #pragma unroll
      for(int an=0;an<4;++an){
        float p = __expf(sacc[an][j] - mnew);
        sacc[an][j] = p;
        psum += p;
      }
      #pragma unroll
      for(int msk=1;msk<16;msk<<=1) psum += __shfl_xor(psum, msk);
      lrow[j] = lrow[j]*corr + psum;
      #pragma unroll
      for(int an=0;an<4;++an) acc_o[an][j] *= corr;
    }
    // P -> LDS (wave-private rows; within-wave write->read through same array)
    #pragma unroll
    for(int an=0;an<4;++an)
      #pragma unroll
      for(int j=0;j<4;++j)
        Ps[(w*16 + l4*4 + j)*LT + an*16 + l15] = f2bfs(sacc[an][j]);
    bf16x8 pa0 = *(const bf16x8*)&Ps[(w*16+l15)*LT + l4*8];
    bf16x8 pa1 = *(const bf16x8*)&Ps[(w*16+l15)*LT + 32 + l4*8];
    #pragma unroll
    for(int an2=0;an2<4;++an2){
      bf16x8 bv0 = *(const bf16x8*)&VTs[(an2*16+l15)*LT + l4*8];
      bf16x8 bv1 = *(const bf16x8*)&VTs[(an2*16+l15)*LT + 32 + l4*8];
      acc_o[an2] = mfma16(pa0, bv0, acc_o[an2]);
      acc_o[an2] = mfma16(pa1, bv1, acc_o[an2]);
    }
  }
  #pragma unroll
  for(int an2=0;an2<4;++an2)
    #pragma unroll
    for(int j=0;j<4;++j){
      int r = qb*64 + w*16 + l4*4 + j;
      float ov = acc_o[an2][j] / lrow[j];
      obuf[((size_t)b*Ss + r)*Dd + h*HD + an2*16 + l15] = f2bf(ov);
    }
}

} // namespace

extern "C" void kernel_launch(void* const* d_in, const int* in_sizes, int n_in,
                              void* d_out, int out_size, void* d_ws, size_t ws_size,
                              hipStream_t stream){
  const float* x      = (const float*)d_in[0];
  const float* c      = (const float*)d_in[1];
  const float* w_qkv  = (const float*)d_in[2];
  const float* b_qkv  = (const float*)d_in[3];
  const float* w_proj = (const float*)d_in[4];
  const float* b_proj = (const float*)d_in[5];
  const float* w12    = (const float*)d_in[6];
  const float* b12    = (const float*)d_in[7];
  const float* w3     = (const float*)d_in[8];
  const float* b3     = (const float*)d_in[9];
  const float* w_ada  = (const float*)d_in[10];
  const float* b_ada  = (const float*)d_in[11];
  const float* n1w    = (const float*)d_in[12];
  const float* n2w    = (const float*)d_in[13];
  const float* qnw    = (const float*)d_in[14];
  const float* knw    = (const float*)d_in[15];
  float* out = (float*)d_out;
  (void)in_sizes; (void)n_in; (void)out_size;

  constexpr size_t WS_NEED = 227254272ull;
  if (ws_size < WS_NEED) return;

  char* ws = (char*)d_ws;
  float*  silu_c = (float*)(ws + 0);            //  64 KiB  f32 [16,1024]
  float*  ada    = (float*)(ws + 65536);        // 384 KiB  f32 [16,6144]
  float2* ropet  = (float2*)(ws + 458752);      // 256 KiB  [1024,32]
  bf16*   wqkvT  = (bf16*)(ws + 720896);        //   6 MiB  [3072,1024]
  bf16*   wprojT = (bf16*)(ws + 7012352);       //   2 MiB  [1024,1024]
  bf16*   w12T   = (bf16*)(ws + 9109504);       //  10.7MiB [5460,1024]
  bf16*   w3T    = (bf16*)(ws + 20291584);      //   5.4MiB [1024,2752] zero-padded
  bf16*   hbuf   = (bf16*)(ws + 25927680);      //  32 MiB  [16384,1024]
  bf16*   qkvb   = (bf16*)(ws + 59482112);      //  96 MiB  [16384,3072]
  float*  xmid   = (float*)(ws + 160145408);    //  64 MiB  [16384,1024] f32
  bf16*   obuf   = hbuf;   // hbuf dead after QKV GEMM
  bf16*   h2     = hbuf;   // obuf dead after proj GEMM
  bf16*   mlpmid = qkvb;   // qkv dead after attention

  k_silu<<<64,256,0,stream>>>(c, silu_c, Bb*Dd);
  k_rope_tab<<<128,256,0,stream>>>(ropet);
  k_ada<<<96,256,0,stream>>>(silu_c, w_ada, b_ada, ada);
  k_transpose<<<dim3(32,96),256,0,stream>>>(w_qkv, wqkvT, 1024, 3072, 1024);
  k_transpose<<<dim3(32,32),256,0,stream>>>(w_proj, wprojT, 1024, 1024, 1024);
  k_transpose<<<dim3(32,171),256,0,stream>>>(w12, w12T, 1024, 5460, 1024);
  k_transpose<<<dim3(86,32),256,0,stream>>>(w3, w3T, 2730, 1024, 2752);

  // attention branch
  k_norm_mod<<<NR,256,0,stream>>>(x, n1w, ada + 0, ada + 1024, hbuf);
  k_gemm<0><<<dim3(128,24),256,0,stream>>>(hbuf,1024, wqkvT,0,1024,
      b_qkv,nullptr, 1024, nullptr,nullptr, qkvb,3072);
  k_qknorm<<<131072,256,0,stream>>>(qkvb, qnw, knw, ropet);
  k_attn<<<dim3(256,16),256,0,stream>>>(qkvb, obuf);
  k_gemm<1><<<dim3(128,8),256,0,stream>>>(obuf,1024, wprojT,0,1024,
      b_proj,nullptr, 1024, x, ada + 2048, xmid,1024);

  // MLP branch
  k_norm_mod<<<NR,256,0,stream>>>(xmid, n2w, ada + 3072, ada + 4096, h2);
  k_gemm<3><<<dim3(128,43),256,0,stream>>>(h2,1024, w12T,(long long)MLPH*1024,1024,
      b12, b12 + MLPH, 1024, nullptr,nullptr, mlpmid, MLPH_PAD);
  k_gemm<1><<<dim3(128,8),256,0,stream>>>(mlpmid,MLPH_PAD, w3T,0,MLPH_PAD,
      b3,nullptr, MLPH_PAD, xmid, ada + 5120, out,1024);
}

// Round 7
// 1049.156 us; speedup vs baseline: 1.6633x; 1.0736x over previous
//
#include <hip/hip_runtime.h>
#include <hip/hip_bf16.h>
#include <math.h>

namespace {

constexpr int Bb = 16;
constexpr int Ss = 1024;
constexpr int Dd = 1024;
constexpr int Hh = 16;
constexpr int HD = 64;
constexpr int MLPH = 2730;
constexpr int MLPH_PAD = 2752;
constexpr int ADA_LD = 6144;
constexpr int NR = Bb * Ss; // 16384 rows

typedef __attribute__((ext_vector_type(8))) short bf16x8;
typedef __attribute__((ext_vector_type(4))) float f32x4;
typedef __hip_bfloat16 bf16;
typedef unsigned int u32;

__device__ __forceinline__ float bf2f(bf16 v){ return __bfloat162float(v); }
__device__ __forceinline__ bf16 f2bf(float v){ return __float2bfloat16(v); }
__device__ __forceinline__ short f2bfs(float v){ bf16 t = __float2bfloat16(v); return __builtin_bit_cast(short, t); }

__device__ __forceinline__ f32x4 mfma16(bf16x8 a, bf16x8 b, f32x4 c){
  return __builtin_amdgcn_mfma_f32_16x16x32_bf16(a, b, c, 0, 0, 0);
}

// async global->LDS, 16B per lane; LDS dest linear (wave base + lane*16)
__device__ __forceinline__ void gload16(const void* g, void* l){
  __builtin_amdgcn_global_load_lds(
      (const __attribute__((address_space(1))) u32*)g,
      (__attribute__((address_space(3))) u32*)l, 16, 0, 0);
}

// ---------------- small kernels ----------------

__global__ void k_silu(const float* __restrict__ c, float* __restrict__ out, int n){
  int i = blockIdx.x*256 + threadIdx.x;
  if(i < n){ float v = c[i]; out[i] = v / (1.f + __expf(-v)); }
}

// grid 96: each block owns 64 cols of ada; 4-way K-split + LDS reduce
__global__ __launch_bounds__(256) void k_ada(const float* __restrict__ sc,
    const float* __restrict__ w, const float* __restrict__ bias, float* __restrict__ ada){
  __shared__ float red[4][Bb][64];
  int tid = threadIdx.x;
  int jj = tid & 63, ks = tid >> 6;
  int j = blockIdx.x*64 + jj;
  float acc[Bb];
  #pragma unroll
  for(int b=0;b<Bb;++b) acc[b] = 0.f;
  for(int k=ks*256; k<ks*256+256; ++k){
    float wv = w[(size_t)k*ADA_LD + j];
    #pragma unroll
    for(int b=0;b<Bb;++b) acc[b] += sc[b*Dd + k] * wv;
  }
  #pragma unroll
  for(int b=0;b<Bb;++b) red[ks][b][jj] = acc[b];
  __syncthreads();
  #pragma unroll
  for(int rep=0;rep<4;++rep){
    int idx = rep*256 + tid;       // 0..1023
    int b = idx >> 6, j2 = idx & 63;
    float s = red[0][b][j2]+red[1][b][j2]+red[2][b][j2]+red[3][b][j2];
    ada[(size_t)b*ADA_LD + blockIdx.x*64 + j2] = s + bias[blockIdx.x*64 + j2];
  }
}

__global__ void k_rope_tab(float2* __restrict__ tab){
  int i = blockIdx.x*256 + threadIdx.x;   // 0..32767 ; i = s*32 + f
  int s = i >> 5, f = i & 31;
  float inv = powf(10000.f, -((float)(2*f)) / 64.f);
  float fr = (float)s * inv;
  float sv, cv;
  sincosf(fr, &sv, &cv);
  tab[i] = make_float2(cv, sv);
}

// in f32 [R,C] -> out bf16 [C,Rpad], zero-filled for col in [R,Rpad)
__global__ void k_transpose(const float* __restrict__ in, bf16* __restrict__ out,
                            int R, int C, int Rpad){
  __shared__ short tile[32][33];
  int tx = threadIdx.x & 31, ty = threadIdx.x >> 5;
  int tr0 = blockIdx.x*32, tc0 = blockIdx.y*32;
  #pragma unroll
  for(int i=0;i<4;++i){
    int r = tr0 + ty + i*8, cc = tc0 + tx;
    short v = 0;
    if(r < R && cc < C) v = f2bfs(in[(size_t)r*C + cc]);
    tile[ty+i*8][tx] = v;
  }
  __syncthreads();
  #pragma unroll
  for(int i=0;i<4;++i){
    int oc = tc0 + ty + i*8;   // out row (former col)
    int orow = tr0 + tx;       // out col (former row)
    if(oc < C && orow < Rpad)
      out[(size_t)oc*Rpad + orow] = __builtin_bit_cast(bf16, tile[tx][ty+i*8]);
  }
}

// RMSNorm over D + adaLN modulate
__global__ __launch_bounds__(256) void k_norm_mod(const float* __restrict__ x,
    const float* __restrict__ w, const float* __restrict__ shift, const float* __restrict__ scale,
    bf16* __restrict__ out){
  int r = blockIdx.x;
  int b = r >> 10;
  int t = threadIdx.x;
  const float* xr = x + (size_t)r*Dd;
  float v[4]; float ss = 0.f;
  #pragma unroll
  for(int i=0;i<4;++i){
    float f = xr[t*4+i];
    v[i] = f; ss += f*f;
  }
  #pragma unroll
  for(int m=1;m<64;m<<=1) ss += __shfl_xor(ss, m);
  __shared__ float red[4];
  if((t & 63) == 0) red[t>>6] = ss;
  __syncthreads();
  float tot = red[0]+red[1]+red[2]+red[3];
  float rms = rsqrtf(tot * (1.f/Dd) + 1e-6f);
  #pragma unroll
  for(int i=0;i<4;++i){
    int ccol = t*4+i;
    float h = v[i]*rms*w[ccol];
    float scv = scale[(size_t)b*ADA_LD + ccol];
    float shv = shift[(size_t)b*ADA_LD + ccol];
    out[(size_t)r*Dd + ccol] = f2bf(h*(1.f+scv) + shv);
  }
}

// per-(b,s,h) RMSNorm(64) + RoPE for q and k rows of qkv, in place
__global__ __launch_bounds__(256) void k_qknorm(bf16* __restrict__ qkv,
    const float* __restrict__ qw, const float* __restrict__ kw, const float2* __restrict__ tab){
  int gid = blockIdx.x*256 + threadIdx.x;
  int lane = gid & 63;
  int wid = gid >> 6;          // 0 .. 524287
  int isK = wid & 1;
  int bsh = wid >> 1;          // 0 .. 262143
  int h = bsh & (Hh-1);
  int bs = bsh >> 4;           // 0..16383
  int s = bs & (Ss-1);
  bf16* p = qkv + (size_t)bs*3072 + isK*Dd + h*HD + lane;
  float vv = bf2f(*p);
  float ss = vv*vv;
  #pragma unroll
  for(int m=1;m<64;m<<=1) ss += __shfl_xor(ss, m);
  float rms = rsqrtf(ss*(1.f/HD) + 1e-6f);
  const float* wn = isK ? kw : qw;
  float xn = vv*rms*wn[lane];
  float other = __shfl_xor(xn, 32);
  float2 cs = tab[s*32 + (lane & 31)];
  float o = (lane < 32) ? (xn*cs.x - other*cs.y) : (other*cs.y + xn*cs.x);
  *p = f2bf(o);
}

// ---------------- GEMM: C[M,N] = A[M,K] * BT[N,K]^T (+ epilogues) ----------------
// 2-phase dbuf, global_load_lds staging, XOR k-slot swizzle (both sides).
// MODE 0: 128x128 tile; out bf16 = acc + bias1[n]
// MODE 1: 128x128 tile; out f32 = res[r,n] + gate[b,n]*(acc + bias1[n])
// MODE 3: 128x64 tile (dual-acc fits 2 waves/SIMD);
//         out bf16 = silu(acc1+bias1[n]) * (acc2+bias2[n]); n in [MLPH,MLPH_PAD) -> 0
template<int MODE>
__global__ __launch_bounds__(256, 2) void k_gemm(
    const bf16* __restrict__ A, int lda,
    const bf16* __restrict__ BT, long long b2off, int ldb,
    const float* __restrict__ bias1, const float* __restrict__ bias2,
    int K,
    const float* __restrict__ res, const float* __restrict__ gate,
    void* __restrict__ outp, int ldo)
{
  constexpr int BN  = (MODE==3) ? 64 : 128;   // block N-extent
  constexpr int NFR = (MODE==3) ? 2  : 4;     // B fragments per wave (wave N = 16*NFR)
  alignas(16) __shared__ short As[2][128*32];
  alignas(16) __shared__ short Bs[2][BN*32];
  alignas(16) __shared__ short Bs2[(MODE==3)?2:1][(MODE==3)?BN*32:8];

  int tid = threadIdx.x;
  int lane = tid & 63, wid = tid >> 6;
  int wm = wid >> 1, wn = wid & 1;
  int l15 = lane & 15, l4 = lane >> 4;
  int brow = blockIdx.x * 128;
  int bcol = blockIdx.y * BN;

  // staging: thread t owns linear LDS slot t (row=t>>2, s=t&3); global source
  // k-chunk k8 = s ^ ((row>>1)&3)  [swizzle involution, read side matches]
  int r0 = tid >> 2, s0 = tid & 3;
  int r1 = r0 + 64;
  int k80 = s0 ^ ((r0 >> 1) & 3);
  int k81 = s0 ^ ((r1 >> 1) & 3);

  const bf16* a0 = A  + (size_t)(brow+r0)*lda + k80*8;
  const bf16* a1 = A  + (size_t)(brow+r1)*lda + k81*8;
  const bf16* b0 = BT + (size_t)(bcol+r0)*ldb + k80*8;
  const bf16* b1 = BT + (size_t)(bcol+r1)*ldb + k81*8;  // used only when BN==128

  f32x4 zero4 = {0.f,0.f,0.f,0.f};
  f32x4 acc[4][NFR], acc2[4][NFR];
  #pragma unroll
  for(int m=0;m<4;++m)
    #pragma unroll
    for(int n=0;n<NFR;++n){ acc[m][n]=zero4; acc2[m][n]=zero4; }

  auto STAGE = [&](int kt, int buf){
    int ko = kt << 5;
    gload16(a0 + ko, &As[buf][tid*8]);
    gload16(a1 + ko, &As[buf][(tid+256)*8]);
    gload16(b0 + ko, &Bs[buf][tid*8]);
    if constexpr (MODE!=3) gload16(b1 + ko, &Bs[buf][(tid+256)*8]);
    if constexpr (MODE==3) gload16(b0 + b2off + ko, &Bs2[buf][tid*8]);
  };

  const int nk = K >> 5;
  STAGE(0, 0);
  __syncthreads();

  int cur = 0;
  for(int kt=0; kt<nk; ++kt){
    if(kt+1 < nk) STAGE(kt+1, cur^1);

    bf16x8 af[4], bfr[NFR], bfr2[NFR];
    #pragma unroll
    for(int m=0;m<4;++m){
      int rr = wm*64 + m*16 + l15;
      int sl = l4 ^ ((rr >> 1) & 3);
      af[m] = *(const bf16x8*)&As[cur][rr*32 + sl*8];
    }
    #pragma unroll
    for(int n=0;n<NFR;++n){
      int rr = wn*(16*NFR) + n*16 + l15;
      int sl = l4 ^ ((rr >> 1) & 3);
      bfr[n] = *(const bf16x8*)&Bs[cur][rr*32 + sl*8];
      if constexpr (MODE==3)
        bfr2[n] = *(const bf16x8*)&Bs2[cur][rr*32 + sl*8];
    }
    #pragma unroll
    for(int m=0;m<4;++m){
      #pragma unroll
      for(int n=0;n<NFR;++n){
        acc[m][n] = mfma16(af[m], bfr[n], acc[m][n]);
        if constexpr (MODE==3) acc2[m][n] = mfma16(af[m], bfr2[n], acc2[m][n]);
      }
    }
    __syncthreads();        // drains prefetch (vmcnt0) + guards buffer reuse
    cur ^= 1;
  }

  // epilogue: C layout col=lane&15, row=(lane>>4)*4+j  [guide-verified]
  #pragma unroll
  for(int m=0;m<4;++m){
    #pragma unroll
    for(int n=0;n<NFR;++n){
      #pragma unroll
      for(int j=0;j<4;++j){
        int r  = brow + wm*64 + m*16 + l4*4 + j;
        int cc = bcol + wn*(16*NFR) + n*16 + l15;
        float v = acc[m][n][j];
        if constexpr (MODE==0){
          v += bias1[cc];
          ((bf16*)outp)[(size_t)r*ldo + cc] = f2bf(v);
        } else if constexpr (MODE==1){
          v += bias1[cc];
          int b = r >> 10;
          float xr = res[(size_t)r*Dd + cc];
          ((float*)outp)[(size_t)r*ldo + cc] = xr + gate[(size_t)b*ADA_LD + cc]*v;
        } else {
          float o = 0.f;
          if(cc < MLPH){
            float v1 = v + bias1[cc];
            float v2 = acc2[m][n][j] + bias2[cc];
            o = (v1/(1.f+__expf(-v1)))*v2;
          }
          ((bf16*)outp)[(size_t)r*ldo + cc] = f2bf(o);
        }
      }
    }
  }
}

// ---------------- flash attention ----------------
// QBLK=128 (wave w owns 32 q-rows, 2 groups of 16), Q in registers,
// K/V reg-staged with T14 prefetch; all LDS conflict-engineered:
//  K : linear writes (tid*16B), chunk-XOR p = c ^ (row&7) on source+read
//  VT: transposed scalar writes, pos ^ ((d>>3)<<3) both sides
//  P : pos ^ (((row>>2)&3)<<4) both sides
// XCD-locality: flat = ((bh>>3)*8 + qb)*8 + (bh&7)
__global__ __launch_bounds__(256) void k_attn(const bf16* __restrict__ qkv, bf16* __restrict__ obuf){
  alignas(16) __shared__ short Ks[64*64];
  alignas(16) __shared__ short VTs[64*64];   // [d][s'] swizzled
  alignas(16) __shared__ short Ps[128*64];

  int flatb = blockIdx.x;          // 0..2047
  int low3 = flatb & 7;
  int rest = flatb >> 3;
  int qb   = rest & 7;             // 8 q-blocks of 128 rows
  int bh   = ((rest >> 3) << 3) | low3;
  int b = bh >> 4, h = bh & 15;

  int tid = threadIdx.x;
  int lane = tid & 63, w = tid >> 6;
  int l15 = lane & 15, l4 = lane >> 4;

  const bf16* base = qkv + (size_t)b*Ss*3072 + h*HD;

  // Q in registers: wave w owns q rows qb*128 + w*32 + hi*16 + l15
  bf16x8 aq[2][2];
  #pragma unroll
  for(int hi=0;hi<2;++hi)
    #pragma unroll
    for(int hf=0;hf<2;++hf)
      aq[hi][hf] = *(const bf16x8*)(base +
          (size_t)(qb*128 + w*32 + hi*16 + l15)*3072 + hf*32 + l4*8);

  // staging geometry: thread -> (row r0(+32ch), chunk c0)
  int r0 = tid >> 3, c0 = tid & 7;
  int khcol = (c0 ^ (r0 & 7)) * 8;   // pre-swizzled K source chunk
  bf16x8 kreg[2], vreg[2];
  #pragma unroll
  for(int ch=0; ch<2; ++ch){
    int rr = r0 + ch*32;
    kreg[ch] = *(const bf16x8*)(base + Dd   + (size_t)rr*3072 + khcol);
    vreg[ch] = *(const bf16x8*)(base + 2*Dd + (size_t)rr*3072 + c0*8);
  }

  f32x4 zero4 = {0.f,0.f,0.f,0.f};
  f32x4 acc_o[2][4];
  float mrow[2][4], lrow[2][4];
  #pragma unroll
  for(int hi=0;hi<2;++hi)
    #pragma unroll
    for(int j=0;j<4;++j){ mrow[hi][j] = -1e30f; lrow[hi][j] = 0.f; acc_o[hi][j] = zero4; }

  for(int kb=0; kb<Ss/64; ++kb){
    if(kb) __syncthreads();          // prior tile's reads complete before overwrite
    #pragma unroll
    for(int ch=0; ch<2; ++ch){
      *(bf16x8*)&Ks[(tid + ch*256)*8] = kreg[ch];      // linear -> conflict-free
      int vr = r0 + ch*32;
      int vswz = vr ^ (c0 << 3);
      #pragma unroll
      for(int i=0;i<8;++i)
        VTs[(c0*8 + i)*64 + vswz] = vreg[ch][i];       // 2 lanes/bank = free
    }
    if(kb+1 < Ss/64){                 // T14: prefetch flies under compute
      #pragma unroll
      for(int ch=0; ch<2; ++ch){
        int rr = (kb+1)*64 + r0 + ch*32;
        kreg[ch] = *(const bf16x8*)(base + Dd   + (size_t)rr*3072 + khcol);
        vreg[ch] = *(const bf16x8*)(base + 2*Dd + (size_t)rr*3072 + c0*8);
      }
    }
    __syncthreads();

    #pragma unroll
    for(int hi=0; hi<2; ++hi){
      f32x4 sacc[4];
      #pragma unroll
      for(int an=0;an<4;++an) sacc[an]=zero4;
      __builtin_amdgcn_s_setprio(1);
      #pragma unroll
      for(int an=0;an<4;++an){
        int R = an*16 + l15;
        bf16x8 bk0 = *(const bf16x8*)&Ks[R*64 + ((l4     ^ (R&7)))*8];
        bf16x8 bk1 = *(const bf16x8*)&Ks[R*64 + (((4|l4) ^ (R&7)))*8];
        sacc[an] = mfma16(aq[hi][0], bk0, sacc[an]);
        sacc[an] = mfma16(aq[hi][1], bk1, sacc[an]);
      }
      __builtin_amdgcn_s_setprio(0);
      #pragma unroll
      for(int j=0;j<4;++j){
        float mx = -1e30f;
        #pragma unroll
        for(int an=0;an<4;++an){ sacc[an][j] *= 0.125f; mx = fmaxf(mx, sacc[an][j]); }
        #pragma unroll
        for(int msk=1;msk<16;msk<<=1) mx = fmaxf(mx, __shfl_xor(mx, msk));
        float mnew = fmaxf(mrow[hi][j], mx);
        float corr = __expf(mrow[hi][j] - mnew);
        mrow[hi][j] = mnew;
        float psum = 0.f;
        #pragma unroll
        for(int an=0;an<4;++an){
          float p = __expf(sacc[an][j] - mnew);
          sacc[an][j] = p; psum += p;
        }
        #pragma unroll
        for(int msk=1;msk<16;msk<<=1) psum += __shfl_xor(psum, msk);
        lrow[hi][j] = lrow[hi][j]*corr + psum;
        #pragma unroll
        for(int an=0;an<4;++an) acc_o[hi][an][j] *= corr;
      }
      // P -> LDS (wave-private rows; swizzled pos)
      #pragma unroll
      for(int an=0;an<4;++an)
        #pragma unroll
        for(int j=0;j<4;++j)
          Ps[(w*32 + hi*16 + l4*4 + j)*64 + ((an*16 + l15) ^ (l4<<4))] = f2bfs(sacc[an][j]);
      int prow = w*32 + hi*16 + l15;
      int pmask = ((l15>>2)&3) << 4;
      bf16x8 pa0 = *(const bf16x8*)&Ps[prow*64 + ((l4*8)      ^ pmask)];
      bf16x8 pa1 = *(const bf16x8*)&Ps[prow*64 + ((32 + l4*8) ^ pmask)];
      __builtin_amdgcn_s_setprio(1);
      #pragma unroll
      for(int an2=0;an2<4;++an2){
        int dR = an2*16 + l15;
        int vmask = ((dR>>3)&7) << 3;
        bf16x8 bv0 = *(const bf16x8*)&VTs[dR*64 + ((l4*8)      ^ vmask)];
        bf16x8 bv1 = *(const bf16x8*)&VTs[dR*64 + ((32 + l4*8) ^ vmask)];
        acc_o[hi][an2] = mfma16(pa0, bv0, acc_o[hi][an2]);
        acc_o[hi][an2] = mfma16(pa1, bv1, acc_o[hi][an2]);
      }
      __builtin_amdgcn_s_setprio(0);
    }
  }
  #pragma unroll
  for(int hi=0;hi<2;++hi)
    #pragma unroll
    for(int an2=0;an2<4;++an2)
      #pragma unroll
      for(int j=0;j<4;++j){
        int r = qb*128 + w*32 + hi*16 + l4*4 + j;
        float ov = acc_o[hi][an2][j] / lrow[hi][j];
        obuf[((size_t)b*Ss + r)*Dd + h*HD + an2*16 + l15] = f2bf(ov);
      }
}

} // namespace

extern "C" void kernel_launch(void* const* d_in, const int* in_sizes, int n_in,
                              void* d_out, int out_size, void* d_ws, size_t ws_size,
                              hipStream_t stream){
  const float* x      = (const float*)d_in[0];
  const float* c      = (const float*)d_in[1];
  const float* w_qkv  = (const float*)d_in[2];
  const float* b_qkv  = (const float*)d_in[3];
  const float* w_proj = (const float*)d_in[4];
  const float* b_proj = (const float*)d_in[5];
  const float* w12    = (const float*)d_in[6];
  const float* b12    = (const float*)d_in[7];
  const float* w3     = (const float*)d_in[8];
  const float* b3     = (const float*)d_in[9];
  const float* w_ada  = (const float*)d_in[10];
  const float* b_ada  = (const float*)d_in[11];
  const float* n1w    = (const float*)d_in[12];
  const float* n2w    = (const float*)d_in[13];
  const float* qnw    = (const float*)d_in[14];
  const float* knw    = (const float*)d_in[15];
  float* out = (float*)d_out;
  (void)in_sizes; (void)n_in; (void)out_size;

  constexpr size_t WS_NEED = 227254272ull;
  if (ws_size < WS_NEED) return;

  char* ws = (char*)d_ws;
  float*  silu_c = (float*)(ws + 0);            //  64 KiB  f32 [16,1024]
  float*  ada    = (float*)(ws + 65536);        // 384 KiB  f32 [16,6144]
  float2* ropet  = (float2*)(ws + 458752);      // 256 KiB  [1024,32]
  bf16*   wqkvT  = (bf16*)(ws + 720896);        //   6 MiB  [3072,1024]
  bf16*   wprojT = (bf16*)(ws + 7012352);       //   2 MiB  [1024,1024]
  bf16*   w12T   = (bf16*)(ws + 9109504);       //  10.7MiB [5460,1024]
  bf16*   w3T    = (bf16*)(ws + 20291584);      //   5.4MiB [1024,2752] zero-padded
  bf16*   hbuf   = (bf16*)(ws + 25927680);      //  32 MiB  [16384,1024]
  bf16*   qkvb   = (bf16*)(ws + 59482112);      //  96 MiB  [16384,3072]
  float*  xmid   = (float*)(ws + 160145408);    //  64 MiB  [16384,1024] f32
  bf16*   obuf   = hbuf;   // hbuf dead after QKV GEMM
  bf16*   h2     = hbuf;   // obuf dead after proj GEMM
  bf16*   mlpmid = qkvb;   // qkv dead after attention

  k_silu<<<64,256,0,stream>>>(c, silu_c, Bb*Dd);
  k_rope_tab<<<128,256,0,stream>>>(ropet);
  k_ada<<<96,256,0,stream>>>(silu_c, w_ada, b_ada, ada);
  k_transpose<<<dim3(32,96),256,0,stream>>>(w_qkv, wqkvT, 1024, 3072, 1024);
  k_transpose<<<dim3(32,32),256,0,stream>>>(w_proj, wprojT, 1024, 1024, 1024);
  k_transpose<<<dim3(32,171),256,0,stream>>>(w12, w12T, 1024, 5460, 1024);
  k_transpose<<<dim3(86,32),256,0,stream>>>(w3, w3T, 2730, 1024, 2752);

  // attention branch
  k_norm_mod<<<NR,256,0,stream>>>(x, n1w, ada + 0, ada + 1024, hbuf);
  k_gemm<0><<<dim3(128,24),256,0,stream>>>(hbuf,1024, wqkvT,0,1024,
      b_qkv,nullptr, 1024, nullptr,nullptr, qkvb,3072);
  k_qknorm<<<131072,256,0,stream>>>(qkvb, qnw, knw, ropet);
  k_attn<<<2048,256,0,stream>>>(qkvb, obuf);
  k_gemm<1><<<dim3(128,8),256,0,stream>>>(obuf,1024, wprojT,0,1024,
      b_proj,nullptr, 1024, x, ada + 2048, xmid,1024);

  // MLP branch
  k_norm_mod<<<NR,256,0,stream>>>(xmid, n2w, ada + 3072, ada + 4096, h2);
  k_gemm<3><<<dim3(128,43),256,0,stream>>>(h2,1024, w12T,(long long)MLPH*1024,1024,
      b12, b12 + MLPH, 1024, nullptr,nullptr, mlpmid, MLPH_PAD);
  k_gemm<1><<<dim3(128,8),256,0,stream>>>(mlpmid,MLPH_PAD, w3T,0,MLPH_PAD,
      b3,nullptr, MLPH_PAD, xmid, ada + 5120, out,1024);
}